// Round 2
// baseline (4279.822 us; speedup 1.0000x reference)
//
#include <hip/hip_runtime.h>
#include <math.h>

#define NN 50000
#define NE 800000
#define NG 64
#define IND 128
#define HID1 64
#define H1HEADS 4
#define D1 256      // H1HEADS*HID1
#define D2 128      // OUT_DIM
#define NEG 0.2f
#define NEG_INF_F (-INFINITY)

__device__ __forceinline__ void atomicMaxF(float* addr, float val) {
    if (val >= 0.f) atomicMax((int*)addr, __float_as_int(val));
    else            atomicMin((unsigned int*)addr, (unsigned int)__float_as_int(val));
}

// ---------------- SGEMM: C[M,N] = A[M,K] @ B[K,N], N%64==0, K%16==0 ----------
__global__ __launch_bounds__(256) void sgemm(int M, int N, int K,
                                             const float* __restrict__ A,
                                             const float* __restrict__ B,
                                             float* __restrict__ C) {
    __shared__ float As[16][65];   // +1 pad: avoid 16-way write conflict
    __shared__ float Bs[16][64];
    const int tid = threadIdx.x;
    const int brow = blockIdx.y * 64, bcol = blockIdx.x * 64;
    const int tr = (tid >> 4) << 2;   // 0..60
    const int tc = (tid & 15) << 2;   // 0..60
    float acc[4][4] = {};
    for (int k0 = 0; k0 < K; k0 += 16) {
        #pragma unroll
        for (int i = tid; i < 64 * 16; i += 256) {
            int r = i >> 4, c = i & 15;
            int gr = brow + r;
            As[c][r] = (gr < M) ? A[(long)gr * K + k0 + c] : 0.f;
        }
        #pragma unroll
        for (int i = tid; i < 16 * 64; i += 256) {
            int r = i >> 6, c = i & 63;
            Bs[r][c] = B[(long)(k0 + r) * N + bcol + c];
        }
        __syncthreads();
        #pragma unroll
        for (int kk = 0; kk < 16; ++kk) {
            float a[4], b[4];
            #pragma unroll
            for (int i = 0; i < 4; ++i) a[i] = As[kk][tr + i];
            #pragma unroll
            for (int j = 0; j < 4; ++j) b[j] = Bs[kk][tc + j];
            #pragma unroll
            for (int i = 0; i < 4; ++i)
                #pragma unroll
                for (int j = 0; j < 4; ++j)
                    acc[i][j] += a[i] * b[j];
        }
        __syncthreads();
    }
    #pragma unroll
    for (int i = 0; i < 4; ++i) {
        int r = brow + tr + i;
        if (r < M) {
            #pragma unroll
            for (int j = 0; j < 4; ++j)
                C[(long)r * N + bcol + tc + j] = acc[i][j];
        }
    }
}

// --------------- per-(node,head) attention score dots ------------------------
template<int H, int C>
__global__ __launch_bounds__(256) void node_scores(const float* __restrict__ Hm,
                                                   const float* __restrict__ a_s,
                                                   const float* __restrict__ a_d,
                                                   float* __restrict__ al_s,
                                                   float* __restrict__ al_d) {
    long gtid = (long)blockIdx.x * blockDim.x + threadIdx.x;
    long wave = gtid >> 6;
    int lane = threadIdx.x & 63;
    int n = (int)(wave / H), h = (int)(wave % H);
    if (n >= NN) return;
    float ss = 0.f, sd = 0.f;
    const float* row = Hm + (long)n * (H * C) + h * C;
    #pragma unroll
    for (int c = lane; c < C; c += 64) {
        float v = row[c];
        ss += v * a_s[h * C + c];
        sd += v * a_d[h * C + c];
    }
    #pragma unroll
    for (int off = 32; off > 0; off >>= 1) {
        ss += __shfl_down(ss, off);
        sd += __shfl_down(sd, off);
    }
    if (lane == 0) { al_s[wave] = ss; al_d[wave] = sd; }
}

__global__ __launch_bounds__(256) void fill_f32(float* p, float v, int n) {
    int i = blockIdx.x * blockDim.x + threadIdx.x;
    if (i < n) p[i] = v;
}

// --------------- edge passes -------------------------------------------------
template<int H>
__global__ __launch_bounds__(256) void edge_max(const int* __restrict__ src,
                                                const int* __restrict__ dst,
                                                const float* __restrict__ al_s,
                                                const float* __restrict__ al_d,
                                                float* __restrict__ m) {
    long i = (long)blockIdx.x * blockDim.x + threadIdx.x;
    const long total = (long)(NE + NN) * H;
    if (i >= total) return;
    int e = (int)(i / H), h = (int)(i % H);
    int s = (e < NE) ? src[e] : (e - NE);
    int d = (e < NE) ? dst[e] : (e - NE);
    float x = al_s[s * H + h] + al_d[d * H + h];
    x = (x >= 0.f) ? x : NEG * x;
    atomicMaxF(&m[d * H + h], x);
}

template<int H>
__global__ __launch_bounds__(256) void edge_expsum(const int* __restrict__ src,
                                                   const int* __restrict__ dst,
                                                   const float* __restrict__ al_s,
                                                   const float* __restrict__ al_d,
                                                   const float* __restrict__ m,
                                                   float* __restrict__ den) {
    long i = (long)blockIdx.x * blockDim.x + threadIdx.x;
    const long total = (long)(NE + NN) * H;
    if (i >= total) return;
    int e = (int)(i / H), h = (int)(i % H);
    int s = (e < NE) ? src[e] : (e - NE);
    int d = (e < NE) ? dst[e] : (e - NE);
    float x = al_s[s * H + h] + al_d[d * H + h];
    x = (x >= 0.f) ? x : NEG * x;
    atomicAdd(&den[d * H + h], expf(x - m[d * H + h]));
}

// wave per edge; each lane handles D/64 consecutive channels (same head)
template<int H, int C>
__global__ __launch_bounds__(256) void edge_scatter(const int* __restrict__ src,
                                                    const int* __restrict__ dst,
                                                    const float* __restrict__ al_s,
                                                    const float* __restrict__ al_d,
                                                    const float* __restrict__ m,
                                                    const float* __restrict__ den,
                                                    const float* __restrict__ Hm,
                                                    float* __restrict__ out) {
    constexpr int D = H * C;
    constexpr int VPL = D / 64;
    long gtid = (long)blockIdx.x * blockDim.x + threadIdx.x;
    long wave = gtid >> 6;
    int lane = threadIdx.x & 63;
    if (wave >= (long)(NE + NN)) return;
    int e = (int)wave;
    int s = (e < NE) ? src[e] : (e - NE);
    int d = (e < NE) ? dst[e] : (e - NE);
    const int h = (lane * VPL) / C;
    float x = al_s[s * H + h] + al_d[d * H + h];
    x = (x >= 0.f) ? x : NEG * x;
    float a = expf(x - m[d * H + h]) / den[d * H + h];
    const float* hr = Hm + (long)s * D + lane * VPL;
    float* orow = out + (long)d * D + lane * VPL;
    #pragma unroll
    for (int j = 0; j < VPL; ++j)
        atomicAdd(&orow[j], a * hr[j]);
}

__global__ __launch_bounds__(256) void bias_relu(float* __restrict__ p,
                                                 const float* __restrict__ b,
                                                 int D, long n) {
    long i = (long)blockIdx.x * blockDim.x + threadIdx.x;
    if (i >= n) return;
    float v = p[i] + b[i % D];
    p[i] = v > 0.f ? v : 0.f;
}

// --------------- pooling -----------------------------------------------------
__global__ __launch_bounds__(256) void pool_sum(const float* __restrict__ out2,
                                                const float* __restrict__ b2,
                                                const int* __restrict__ batch,
                                                float* __restrict__ pool) {
    long i = (long)blockIdx.x * blockDim.x + threadIdx.x;
    if (i >= (long)NN * D2) return;
    int n = (int)(i >> 7), c = (int)(i & 127);
    atomicAdd(&pool[batch[n] * D2 + c], out2[i] + b2[c]);
}

__global__ __launch_bounds__(256) void pool_cnt(const int* __restrict__ batch,
                                                float* __restrict__ cnt) {
    int n = blockIdx.x * blockDim.x + threadIdx.x;
    if (n < NN) atomicAdd(&cnt[batch[n]], 1.f);
}

__global__ __launch_bounds__(256) void pool_div(const float* __restrict__ pool,
                                                const float* __restrict__ cnt,
                                                float* __restrict__ out) {
    int i = blockIdx.x * blockDim.x + threadIdx.x;
    if (i < NG * D2) out[i] = pool[i] / fmaxf(cnt[i >> 7], 1.f);
}

extern "C" void kernel_launch(void* const* d_in, const int* in_sizes, int n_in,
                              void* d_out, int out_size, void* d_ws, size_t ws_size,
                              hipStream_t stream) {
    const float* x      = (const float*)d_in[0];
    const int*   src    = (const int*)d_in[1];
    const int*   dst    = (const int*)d_in[2];
    const int*   batch  = (const int*)d_in[3];
    const float* W1     = (const float*)d_in[4];
    const float* a_src1 = (const float*)d_in[5];
    const float* a_dst1 = (const float*)d_in[6];
    const float* b1     = (const float*)d_in[7];
    const float* W2     = (const float*)d_in[8];
    const float* a_src2 = (const float*)d_in[9];
    const float* a_dst2 = (const float*)d_in[10];
    const float* b2     = (const float*)d_in[11];
    float* out = (float*)d_out;

    float* ws   = (float*)d_ws;
    float* Hm1  = ws;                       // [NN, 256]
    float* out1 = Hm1  + (long)NN * D1;     // [NN, 256]
    float* Hm2  = out1 + (long)NN * D1;     // [NN, 128]
    float* out2 = Hm1;                      // alias: H1 dead after scatter1
    float* als1 = Hm2  + (long)NN * D2;     // [NN,4]
    float* ald1 = als1 + NN * H1HEADS;
    float* m1   = ald1 + NN * H1HEADS;
    float* den1 = m1   + NN * H1HEADS;
    float* als2 = den1 + NN * H1HEADS;      // [NN]
    float* ald2 = als2 + NN;
    float* m2   = ald2 + NN;
    float* den2 = m2   + NN;
    float* pool = den2 + NN;                // [64,128]
    float* cnt  = pool + NG * D2;           // [64]

    const long ETOT = NE + NN;

    // ---- layer 1 ----
    {
        dim3 g(D1 / 64, (NN + 63) / 64);
        sgemm<<<g, 256, 0, stream>>>(NN, D1, IND, x, W1, Hm1);
    }
    node_scores<H1HEADS, HID1><<<(int)(((long)NN * H1HEADS * 64 + 255) / 256), 256, 0, stream>>>(
        Hm1, a_src1, a_dst1, als1, ald1);
    (void)hipMemsetAsync(out1, 0, (long)NN * D1 * 4, stream);
    (void)hipMemsetAsync(den1, 0, NN * H1HEADS * 4, stream);
    fill_f32<<<(NN * H1HEADS + 255) / 256, 256, 0, stream>>>(m1, NEG_INF_F, NN * H1HEADS);
    {
        int blocks = (int)((ETOT * H1HEADS + 255) / 256);
        edge_max<H1HEADS><<<blocks, 256, 0, stream>>>(src, dst, als1, ald1, m1);
        edge_expsum<H1HEADS><<<blocks, 256, 0, stream>>>(src, dst, als1, ald1, m1, den1);
    }
    edge_scatter<H1HEADS, HID1><<<(int)((ETOT * 64 + 255) / 256), 256, 0, stream>>>(
        src, dst, als1, ald1, m1, den1, Hm1, out1);
    bias_relu<<<(int)(((long)NN * D1 + 255) / 256), 256, 0, stream>>>(out1, b1, D1, (long)NN * D1);

    // ---- layer 2 ----
    {
        dim3 g(D2 / 64, (NN + 63) / 64);
        sgemm<<<g, 256, 0, stream>>>(NN, D2, D1, out1, W2, Hm2);
    }
    node_scores<1, D2><<<(int)(((long)NN * 64 + 255) / 256), 256, 0, stream>>>(
        Hm2, a_src2, a_dst2, als2, ald2);
    (void)hipMemsetAsync(out2, 0, (long)NN * D2 * 4, stream);   // Hm1 region, dead now
    (void)hipMemsetAsync(den2, 0, NN * 4, stream);
    fill_f32<<<(NN + 255) / 256, 256, 0, stream>>>(m2, NEG_INF_F, NN);
    {
        int blocks = (int)((ETOT + 255) / 256);
        edge_max<1><<<blocks, 256, 0, stream>>>(src, dst, als2, ald2, m2);
        edge_expsum<1><<<blocks, 256, 0, stream>>>(src, dst, als2, ald2, m2, den2);
    }
    edge_scatter<1, D2><<<(int)((ETOT * 64 + 255) / 256), 256, 0, stream>>>(
        src, dst, als2, ald2, m2, den2, Hm2, out2);

    // ---- pool ----
    (void)hipMemsetAsync(pool, 0, NG * D2 * 4, stream);
    (void)hipMemsetAsync(cnt, 0, NG * 4, stream);
    pool_sum<<<(int)(((long)NN * D2 + 255) / 256), 256, 0, stream>>>(out2, b2, batch, pool);
    pool_cnt<<<(NN + 255) / 256, 256, 0, stream>>>(batch, cnt);
    pool_div<<<(NG * D2 + 255) / 256, 256, 0, stream>>>(pool, cnt, out);
}

// Round 3
// 729.984 us; speedup vs baseline: 5.8629x; 5.8629x over previous
//
#include <hip/hip_runtime.h>
#include <math.h>

#define NN 50000
#define NE 800000
#define ETOT (NE + NN)
#define NG 64
#define IND 128
#define HID1 64
#define H1HEADS 4
#define D1 256      // H1HEADS*HID1
#define D2 128      // OUT_DIM
#define NEG 0.2f

// ---------------- SGEMM: C[M,N] = A[M,K] @ B[K,N], N%64==0, K%16==0 ----------
__global__ __launch_bounds__(256) void sgemm(int M, int N, int K,
                                             const float* __restrict__ A,
                                             const float* __restrict__ B,
                                             float* __restrict__ C) {
    __shared__ float As[16][65];
    __shared__ float Bs[16][64];
    const int tid = threadIdx.x;
    const int brow = blockIdx.y * 64, bcol = blockIdx.x * 64;
    const int tr = (tid >> 4) << 2;
    const int tc = (tid & 15) << 2;
    float acc[4][4] = {};
    for (int k0 = 0; k0 < K; k0 += 16) {
        #pragma unroll
        for (int i = tid; i < 64 * 16; i += 256) {
            int r = i >> 4, c = i & 15;
            int gr = brow + r;
            As[c][r] = (gr < M) ? A[(long)gr * K + k0 + c] : 0.f;
        }
        #pragma unroll
        for (int i = tid; i < 16 * 64; i += 256) {
            int r = i >> 6, c = i & 63;
            Bs[r][c] = B[(long)(k0 + r) * N + bcol + c];
        }
        __syncthreads();
        #pragma unroll
        for (int kk = 0; kk < 16; ++kk) {
            float a[4], b[4];
            #pragma unroll
            for (int i = 0; i < 4; ++i) a[i] = As[kk][tr + i];
            #pragma unroll
            for (int j = 0; j < 4; ++j) b[j] = Bs[kk][tc + j];
            #pragma unroll
            for (int i = 0; i < 4; ++i)
                #pragma unroll
                for (int j = 0; j < 4; ++j)
                    acc[i][j] += a[i] * b[j];
        }
        __syncthreads();
    }
    #pragma unroll
    for (int i = 0; i < 4; ++i) {
        int r = brow + tr + i;
        if (r < M) {
            #pragma unroll
            for (int j = 0; j < 4; ++j)
                C[(long)r * N + bcol + tc + j] = acc[i][j];
        }
    }
}

// --------------- per-(node,head) attention score dots ------------------------
template<int H, int C>
__global__ __launch_bounds__(256) void node_scores(const float* __restrict__ Hm,
                                                   const float* __restrict__ a_s,
                                                   const float* __restrict__ a_d,
                                                   float* __restrict__ al_s,
                                                   float* __restrict__ al_d) {
    long gtid = (long)blockIdx.x * blockDim.x + threadIdx.x;
    long wave = gtid >> 6;
    int lane = threadIdx.x & 63;
    int n = (int)(wave / H), h = (int)(wave % H);
    if (n >= NN) return;
    float ss = 0.f, sd = 0.f;
    const float* row = Hm + (long)n * (H * C) + h * C;
    #pragma unroll
    for (int c = lane; c < C; c += 64) {
        float v = row[c];
        ss += v * a_s[h * C + c];
        sd += v * a_d[h * C + c];
    }
    #pragma unroll
    for (int off = 32; off > 0; off >>= 1) {
        ss += __shfl_down(ss, off);
        sd += __shfl_down(sd, off);
    }
    if (lane == 0) { al_s[wave] = ss; al_d[wave] = sd; }
}

// --------------- CSR build ---------------------------------------------------
__global__ __launch_bounds__(256) void csr_hist(const int* __restrict__ dst,
                                                int* __restrict__ deg) {
    int i = blockIdx.x * 256 + threadIdx.x;
    if (i >= ETOT) return;
    int d = (i < NE) ? dst[i] : (i - NE);
    atomicAdd(&deg[d], 1);
}

// single-block exclusive scan over NN degrees -> offp[NN+1]
__global__ __launch_bounds__(1024) void scan_deg(const int* __restrict__ deg,
                                                 int* __restrict__ offp) {
    __shared__ int wsum[16];
    __shared__ int carry_s;
    const int tid = threadIdx.x, lane = tid & 63, w = tid >> 6;
    if (tid == 0) carry_s = 0;
    __syncthreads();
    for (int base = 0; base < NN; base += 1024) {
        int i = base + tid;
        int v = (i < NN) ? deg[i] : 0;
        int s = v;
        #pragma unroll
        for (int o = 1; o < 64; o <<= 1) {
            int t = __shfl_up(s, o);
            if (lane >= o) s += t;
        }
        if (lane == 63) wsum[w] = s;
        __syncthreads();
        if (w == 0 && lane < 16) {
            int t = wsum[lane];
            #pragma unroll
            for (int o = 1; o < 16; o <<= 1) {
                int u = __shfl_up(t, o, 16);
                if ((lane & 15) >= o) t += u;
            }
            wsum[lane] = t;
        }
        __syncthreads();
        int wave_off = (w > 0) ? wsum[w - 1] : 0;
        int carry = carry_s;
        if (i < NN) offp[i] = carry + wave_off + (s - v);
        __syncthreads();
        if (tid == 1023) carry_s = carry + wsum[15];
        __syncthreads();
    }
    if (tid == 0) offp[NN] = carry_s;
}

// cur must be zeroed; stores SRC node id per CSR slot
__global__ __launch_bounds__(256) void csr_fill(const int* __restrict__ src,
                                                const int* __restrict__ dst,
                                                const int* __restrict__ offp,
                                                int* __restrict__ cur,
                                                int* __restrict__ csr) {
    int i = blockIdx.x * 256 + threadIdx.x;
    if (i >= ETOT) return;
    int s = (i < NE) ? src[i] : (i - NE);
    int d = (i < NE) ? dst[i] : (i - NE);
    int slot = atomicAdd(&cur[d], 1);
    csr[offp[d] + slot] = s;
}

// --------------- fused softmax + aggregate gather ----------------------------
// one wave per dst node; lanes own D/64 consecutive channels; online softmax
template<int H, int C, int RELU>
__global__ __launch_bounds__(256) void gat_gather(const int* __restrict__ offp,
                                                  const int* __restrict__ csr,
                                                  const float* __restrict__ als,
                                                  const float* __restrict__ ald,
                                                  const float* __restrict__ Hm,
                                                  const float* __restrict__ bias,
                                                  float* __restrict__ outp) {
    constexpr int D = H * C;
    constexpr int VPL = D / 64;
    const int lane = threadIdx.x & 63;
    const int n = blockIdx.x * 4 + (threadIdx.x >> 6);
    if (n >= NN) return;
    const int h = (lane * VPL) / C;   // head owning this lane's channels

    float aldv[H], m[H], den[H];
    #pragma unroll
    for (int hh = 0; hh < H; ++hh) {
        aldv[hh] = ald[(long)n * H + hh];
        m[hh] = -INFINITY;
        den[hh] = 0.f;
    }
    float acc[VPL] = {};

    const int e0 = offp[n], e1 = offp[n + 1];
    for (int base = e0; base < e1; base += 64) {
        const int cntc = min(64, e1 - base);
        const bool valid = lane < cntc;
        const int s_l = valid ? csr[base + lane] : 0;
        float wv[H], scv[H];
        #pragma unroll
        for (int hh = 0; hh < H; ++hh) {
            float x = als[(long)s_l * H + hh] + aldv[hh];
            x = (x >= 0.f) ? x : NEG * x;
            x = valid ? x : -INFINITY;
            float cm = x;
            #pragma unroll
            for (int o = 32; o > 0; o >>= 1) cm = fmaxf(cm, __shfl_xor(cm, o));
            float nm = fmaxf(m[hh], cm);
            scv[hh] = expf(m[hh] - nm);          // 0 on first chunk
            float wl = valid ? expf(x - nm) : 0.f;
            float ws_ = wl;
            #pragma unroll
            for (int o = 32; o > 0; o >>= 1) ws_ += __shfl_xor(ws_, o);
            den[hh] = den[hh] * scv[hh] + ws_;
            m[hh] = nm;
            wv[hh] = wl;
        }
        float sc_own = scv[0];
        #pragma unroll
        for (int i = 1; i < H; ++i) sc_own = (h == i) ? scv[i] : sc_own;
        #pragma unroll
        for (int k = 0; k < VPL; ++k) acc[k] *= sc_own;

        for (int j = 0; j < cntc; ++j) {
            int se = __shfl(s_l, j);
            float tmp[H];
            #pragma unroll
            for (int hh = 0; hh < H; ++hh) tmp[hh] = __shfl(wv[hh], j);
            float we = tmp[0];
            #pragma unroll
            for (int i = 1; i < H; ++i) we = (h == i) ? tmp[i] : we;
            const float* hrow = Hm + (long)se * D + lane * VPL;
            if constexpr (VPL == 4) {
                float4 v = *reinterpret_cast<const float4*>(hrow);
                acc[0] += we * v.x; acc[1] += we * v.y;
                acc[2] += we * v.z; acc[3] += we * v.w;
            } else {
                float2 v = *reinterpret_cast<const float2*>(hrow);
                acc[0] += we * v.x; acc[1] += we * v.y;
            }
        }
    }
    float dn = den[0];
    #pragma unroll
    for (int i = 1; i < H; ++i) dn = (h == i) ? den[i] : dn;
    float inv = 1.f / dn;
    #pragma unroll
    for (int k = 0; k < VPL; ++k) {
        float v = acc[k] * inv + bias[lane * VPL + k];
        if (RELU) v = fmaxf(v, 0.f);
        outp[(long)n * D + lane * VPL + k] = v;
    }
}

// --------------- pooling -----------------------------------------------------
__global__ __launch_bounds__(256) void pool_sum(const float* __restrict__ out2,
                                                const int* __restrict__ batch,
                                                float* __restrict__ pool) {
    long i = (long)blockIdx.x * blockDim.x + threadIdx.x;
    if (i >= (long)NN * D2) return;
    int n = (int)(i >> 7), c = (int)(i & 127);
    atomicAdd(&pool[batch[n] * D2 + c], out2[i]);
}

__global__ __launch_bounds__(256) void pool_cnt(const int* __restrict__ batch,
                                                float* __restrict__ cnt) {
    int n = blockIdx.x * blockDim.x + threadIdx.x;
    if (n < NN) atomicAdd(&cnt[batch[n]], 1.f);
}

__global__ __launch_bounds__(256) void pool_div(const float* __restrict__ pool,
                                                const float* __restrict__ cnt,
                                                float* __restrict__ out) {
    int i = blockIdx.x * blockDim.x + threadIdx.x;
    if (i < NG * D2) out[i] = pool[i] / fmaxf(cnt[i >> 7], 1.f);
}

extern "C" void kernel_launch(void* const* d_in, const int* in_sizes, int n_in,
                              void* d_out, int out_size, void* d_ws, size_t ws_size,
                              hipStream_t stream) {
    const float* x      = (const float*)d_in[0];
    const int*   src    = (const int*)d_in[1];
    const int*   dst    = (const int*)d_in[2];
    const int*   batch  = (const int*)d_in[3];
    const float* W1     = (const float*)d_in[4];
    const float* a_src1 = (const float*)d_in[5];
    const float* a_dst1 = (const float*)d_in[6];
    const float* b1     = (const float*)d_in[7];
    const float* W2     = (const float*)d_in[8];
    const float* a_src2 = (const float*)d_in[9];
    const float* a_dst2 = (const float*)d_in[10];
    const float* b2     = (const float*)d_in[11];
    float* out = (float*)d_out;

    // workspace layout (total ~33.30M elems = 133.2 MB)
    float* ws   = (float*)d_ws;
    float* Hm1  = ws;                       // [NN*256]
    float* out1 = Hm1  + (long)NN * D1;     // [NN*256]
    float* Hm2  = out1 + (long)NN * D1;     // [NN*128]
    float* out2 = Hm1;                      // alias: Hm1 dead after gather1
    float* als1 = Hm2  + (long)NN * D2;     // [NN*4]
    float* ald1 = als1 + (long)NN * H1HEADS;// [NN*4]
    // layer-2 small arrays alias the (then-dead) als1/ald1 block
    float* als2 = als1;                     // [NN]
    float* ald2 = als1 + NN;                // [NN]
    float* pool = als1 + 2 * NN;            // [NG*D2]
    float* cnt  = pool + NG * D2;           // [NG]
    int* deg  = (int*)(ald1 + (long)NN * H1HEADS);  // [NN] (also reused as fill cursor)
    int* offp = deg + NN;                   // [NN+1]
    int* csr  = offp + NN + 1;              // [ETOT]

    // ---- CSR build (shared by both layers) ----
    (void)hipMemsetAsync(deg, 0, NN * sizeof(int), stream);
    csr_hist<<<(ETOT + 255) / 256, 256, 0, stream>>>(dst, deg);
    scan_deg<<<1, 1024, 0, stream>>>(deg, offp);
    (void)hipMemsetAsync(deg, 0, NN * sizeof(int), stream);   // reuse as cursor
    csr_fill<<<(ETOT + 255) / 256, 256, 0, stream>>>(src, dst, offp, deg, csr);

    // ---- layer 1 ----
    {
        dim3 g(D1 / 64, (NN + 63) / 64);
        sgemm<<<g, 256, 0, stream>>>(NN, D1, IND, x, W1, Hm1);
    }
    node_scores<H1HEADS, HID1><<<(int)(((long)NN * H1HEADS * 64 + 255) / 256), 256, 0, stream>>>(
        Hm1, a_src1, a_dst1, als1, ald1);
    gat_gather<H1HEADS, HID1, 1><<<(NN + 3) / 4, 256, 0, stream>>>(
        offp, csr, als1, ald1, Hm1, b1, out1);

    // ---- layer 2 ----
    {
        dim3 g(D2 / 64, (NN + 63) / 64);
        sgemm<<<g, 256, 0, stream>>>(NN, D2, D1, out1, W2, Hm2);
    }
    node_scores<1, D2><<<(int)(((long)NN * 64 + 255) / 256), 256, 0, stream>>>(
        Hm2, a_src2, a_dst2, als2, ald2);
    gat_gather<1, D2, 0><<<(NN + 3) / 4, 256, 0, stream>>>(
        offp, csr, als2, ald2, Hm2, b2, out2);

    // ---- pool ----
    (void)hipMemsetAsync(pool, 0, NG * D2 * sizeof(float), stream);
    (void)hipMemsetAsync(cnt, 0, NG * sizeof(float), stream);
    pool_sum<<<(int)(((long)NN * D2 + 255) / 256), 256, 0, stream>>>(out2, batch, pool);
    pool_cnt<<<(NN + 255) / 256, 256, 0, stream>>>(batch, cnt);
    pool_div<<<(NG * D2 + 255) / 256, 256, 0, stream>>>(pool, cnt, out);
}

// Round 4
// 553.191 us; speedup vs baseline: 7.7366x; 1.3196x over previous
//
#include <hip/hip_runtime.h>
#include <math.h>

#define NN 50000
#define NE 800000
#define ETOT (NE + NN)
#define NG 64
#define IND 128
#define HID1 64
#define H1HEADS 4
#define D1 256      // H1HEADS*HID1
#define D2 128      // OUT_DIM
#define NEG 0.2f

// ---------------- SGEMM: C[M,N] = A[M,K] @ B[K,N], N%64==0, K%16==0 ----------
__global__ __launch_bounds__(256) void sgemm(int M, int N, int K,
                                             const float* __restrict__ A,
                                             const float* __restrict__ B,
                                             float* __restrict__ C) {
    __shared__ float As[16][65];
    __shared__ float Bs[16][64];
    const int tid = threadIdx.x;
    const int brow = blockIdx.y * 64, bcol = blockIdx.x * 64;
    const int tr = (tid >> 4) << 2;
    const int tc = (tid & 15) << 2;
    float acc[4][4] = {};
    for (int k0 = 0; k0 < K; k0 += 16) {
        #pragma unroll
        for (int i = tid; i < 64 * 16; i += 256) {
            int r = i >> 4, c = i & 15;
            int gr = brow + r;
            As[c][r] = (gr < M) ? A[(long)gr * K + k0 + c] : 0.f;
        }
        #pragma unroll
        for (int i = tid; i < 16 * 64; i += 256) {
            int r = i >> 6, c = i & 63;
            Bs[r][c] = B[(long)(k0 + r) * N + bcol + c];
        }
        __syncthreads();
        #pragma unroll
        for (int kk = 0; kk < 16; ++kk) {
            float a[4], b[4];
            #pragma unroll
            for (int i = 0; i < 4; ++i) a[i] = As[kk][tr + i];
            #pragma unroll
            for (int j = 0; j < 4; ++j) b[j] = Bs[kk][tc + j];
            #pragma unroll
            for (int i = 0; i < 4; ++i)
                #pragma unroll
                for (int j = 0; j < 4; ++j)
                    acc[i][j] += a[i] * b[j];
        }
        __syncthreads();
    }
    #pragma unroll
    for (int i = 0; i < 4; ++i) {
        int r = brow + tr + i;
        if (r < M) {
            #pragma unroll
            for (int j = 0; j < 4; ++j)
                C[(long)r * N + bcol + tc + j] = acc[i][j];
        }
    }
}

// --------------- per-(node,head) attention score dots ------------------------
template<int H, int C>
__global__ __launch_bounds__(256) void node_scores(const float* __restrict__ Hm,
                                                   const float* __restrict__ a_s,
                                                   const float* __restrict__ a_d,
                                                   float* __restrict__ al_s,
                                                   float* __restrict__ al_d) {
    long gtid = (long)blockIdx.x * blockDim.x + threadIdx.x;
    long wave = gtid >> 6;
    int lane = threadIdx.x & 63;
    int n = (int)(wave / H), h = (int)(wave % H);
    if (n >= NN) return;
    float ss = 0.f, sd = 0.f;
    const float* row = Hm + (long)n * (H * C) + h * C;
    #pragma unroll
    for (int c = lane; c < C; c += 64) {
        float v = row[c];
        ss += v * a_s[h * C + c];
        sd += v * a_d[h * C + c];
    }
    #pragma unroll
    for (int off = 32; off > 0; off >>= 1) {
        ss += __shfl_down(ss, off);
        sd += __shfl_down(sd, off);
    }
    if (lane == 0) { al_s[wave] = ss; al_d[wave] = sd; }
}

// --------------- CSR build ---------------------------------------------------
__global__ __launch_bounds__(256) void csr_hist(const int* __restrict__ dst,
                                                int* __restrict__ deg) {
    int i = blockIdx.x * 256 + threadIdx.x;
    if (i >= ETOT) return;
    int d = (i < NE) ? dst[i] : (i - NE);
    atomicAdd(&deg[d], 1);
}

// single-block exclusive scan over NN degrees -> offp[NN+1]
__global__ __launch_bounds__(1024) void scan_deg(const int* __restrict__ deg,
                                                 int* __restrict__ offp) {
    __shared__ int wsum[16];
    __shared__ int carry_s;
    const int tid = threadIdx.x, lane = tid & 63, w = tid >> 6;
    if (tid == 0) carry_s = 0;
    __syncthreads();
    for (int base = 0; base < NN; base += 1024) {
        int i = base + tid;
        int v = (i < NN) ? deg[i] : 0;
        int s = v;
        #pragma unroll
        for (int o = 1; o < 64; o <<= 1) {
            int t = __shfl_up(s, o);
            if (lane >= o) s += t;
        }
        if (lane == 63) wsum[w] = s;
        __syncthreads();
        if (w == 0 && lane < 16) {
            int t = wsum[lane];
            #pragma unroll
            for (int o = 1; o < 16; o <<= 1) {
                int u = __shfl_up(t, o, 16);
                if ((lane & 15) >= o) t += u;
            }
            wsum[lane] = t;
        }
        __syncthreads();
        int wave_off = (w > 0) ? wsum[w - 1] : 0;
        int carry = carry_s;
        if (i < NN) offp[i] = carry + wave_off + (s - v);
        __syncthreads();
        if (tid == 1023) carry_s = carry + wsum[15];
        __syncthreads();
    }
    if (tid == 0) offp[NN] = carry_s;
}

// cur must be zeroed; stores SRC node id per CSR slot
__global__ __launch_bounds__(256) void csr_fill(const int* __restrict__ src,
                                                const int* __restrict__ dst,
                                                const int* __restrict__ offp,
                                                int* __restrict__ cur,
                                                int* __restrict__ csr) {
    int i = blockIdx.x * 256 + threadIdx.x;
    if (i >= ETOT) return;
    int s = (i < NE) ? src[i] : (i - NE);
    int d = (i < NE) ? dst[i] : (i - NE);
    int slot = atomicAdd(&cur[d], 1);
    csr[offp[d] + slot] = s;
}

// --------------- fused softmax + aggregate gather ----------------------------
// one wave per dst node; lanes own D/64 consecutive channels; online softmax
template<int H, int C, int RELU>
__global__ __launch_bounds__(256) void gat_gather(const int* __restrict__ offp,
                                                  const int* __restrict__ csr,
                                                  const float* __restrict__ als,
                                                  const float* __restrict__ ald,
                                                  const float* __restrict__ Hm,
                                                  const float* __restrict__ bias,
                                                  float* __restrict__ outp) {
    constexpr int D = H * C;
    constexpr int VPL = D / 64;
    const int lane = threadIdx.x & 63;
    const int n = blockIdx.x * 4 + (threadIdx.x >> 6);
    if (n >= NN) return;
    const int h = (lane * VPL) / C;   // head owning this lane's channels

    float aldv[H], m[H], den[H];
    #pragma unroll
    for (int hh = 0; hh < H; ++hh) {
        aldv[hh] = ald[(long)n * H + hh];
        m[hh] = -INFINITY;
        den[hh] = 0.f;
    }
    float acc[VPL] = {};

    const int e0 = offp[n], e1 = offp[n + 1];
    for (int base = e0; base < e1; base += 64) {
        const int cntc = min(64, e1 - base);
        const bool valid = lane < cntc;
        const int s_l = valid ? csr[base + lane] : 0;
        float wv[H], scv[H];
        #pragma unroll
        for (int hh = 0; hh < H; ++hh) {
            float x = als[(long)s_l * H + hh] + aldv[hh];
            x = (x >= 0.f) ? x : NEG * x;
            x = valid ? x : -INFINITY;
            float cm = x;
            #pragma unroll
            for (int o = 32; o > 0; o >>= 1) cm = fmaxf(cm, __shfl_xor(cm, o));
            float nm = fmaxf(m[hh], cm);
            scv[hh] = expf(m[hh] - nm);          // 0 on first chunk
            float wl = valid ? expf(x - nm) : 0.f;
            float ws_ = wl;
            #pragma unroll
            for (int o = 32; o > 0; o >>= 1) ws_ += __shfl_xor(ws_, o);
            den[hh] = den[hh] * scv[hh] + ws_;
            m[hh] = nm;
            wv[hh] = wl;
        }
        float sc_own = scv[0];
        #pragma unroll
        for (int i = 1; i < H; ++i) sc_own = (h == i) ? scv[i] : sc_own;
        #pragma unroll
        for (int k = 0; k < VPL; ++k) acc[k] *= sc_own;

        for (int j = 0; j < cntc; ++j) {
            int se = __shfl(s_l, j);
            float tmp[H];
            #pragma unroll
            for (int hh = 0; hh < H; ++hh) tmp[hh] = __shfl(wv[hh], j);
            float we = tmp[0];
            #pragma unroll
            for (int i = 1; i < H; ++i) we = (h == i) ? tmp[i] : we;
            const float* hrow = Hm + (long)se * D + lane * VPL;
            if constexpr (VPL == 4) {
                float4 v = *reinterpret_cast<const float4*>(hrow);
                acc[0] += we * v.x; acc[1] += we * v.y;
                acc[2] += we * v.z; acc[3] += we * v.w;
            } else {
                float2 v = *reinterpret_cast<const float2*>(hrow);
                acc[0] += we * v.x; acc[1] += we * v.y;
            }
        }
    }
    float dn = den[0];
    #pragma unroll
    for (int i = 1; i < H; ++i) dn = (h == i) ? den[i] : dn;
    float inv = 1.f / dn;
    #pragma unroll
    for (int k = 0; k < VPL; ++k) {
        float v = acc[k] * inv + bias[lane * VPL + k];
        if (RELU) v = fmaxf(v, 0.f);
        outp[(long)n * D + lane * VPL + k] = v;
    }
}

// --------------- pooling (atomic-free: batch is sorted) ----------------------
__global__ __launch_bounds__(128) void graph_bounds(const int* __restrict__ batch,
                                                    int* __restrict__ gstart) {
    int g = threadIdx.x;
    if (g > NG) return;
    int lo = 0, hi = NN;
    while (lo < hi) {
        int mid = (lo + hi) >> 1;
        if (batch[mid] < g) lo = mid + 1; else hi = mid;
    }
    gstart[g] = lo;
}

// one block per graph: 4 row-groups x 128 channels, LDS combine, divide
__global__ __launch_bounds__(512) void pool_graph(const float* __restrict__ out2,
                                                  const int* __restrict__ gstart,
                                                  float* __restrict__ out) {
    __shared__ float part[4][128];
    const int g = blockIdx.x;
    const int ch = threadIdx.x & 127;
    const int q = threadIdx.x >> 7;      // 0..3
    const int s = gstart[g], e = gstart[g + 1];
    float acc = 0.f;
    for (int r = s + q; r < e; r += 4)
        acc += out2[(long)r * D2 + ch];
    part[q][ch] = acc;
    __syncthreads();
    if (q == 0) {
        float v = part[0][ch] + part[1][ch] + part[2][ch] + part[3][ch];
        out[g * D2 + ch] = v / fmaxf((float)(e - s), 1.f);
    }
}

extern "C" void kernel_launch(void* const* d_in, const int* in_sizes, int n_in,
                              void* d_out, int out_size, void* d_ws, size_t ws_size,
                              hipStream_t stream) {
    const float* x      = (const float*)d_in[0];
    const int*   src    = (const int*)d_in[1];
    const int*   dst    = (const int*)d_in[2];
    const int*   batch  = (const int*)d_in[3];
    const float* W1     = (const float*)d_in[4];
    const float* a_src1 = (const float*)d_in[5];
    const float* a_dst1 = (const float*)d_in[6];
    const float* b1     = (const float*)d_in[7];
    const float* W2     = (const float*)d_in[8];
    const float* a_src2 = (const float*)d_in[9];
    const float* a_dst2 = (const float*)d_in[10];
    const float* b2     = (const float*)d_in[11];
    float* out = (float*)d_out;

    // workspace layout (~33.35M elems = 133.4 MB)
    float* ws   = (float*)d_ws;
    float* Hm1  = ws;                       // [NN*256]
    float* out1 = Hm1  + (long)NN * D1;     // [NN*256]
    float* Hm2  = out1 + (long)NN * D1;     // [NN*128]
    float* out2 = Hm1;                      // alias: Hm1 dead after gather1
    float* als1 = Hm2  + (long)NN * D2;     // [NN*4]
    float* ald1 = als1 + (long)NN * H1HEADS;// [NN*4]
    float* als2 = als1;                     // [NN] (layer-1 scores dead by then)
    float* ald2 = als1 + NN;                // [NN]
    int* deg    = (int*)(ald1 + (long)NN * H1HEADS);  // [NN] (also fill cursor)
    int* offp   = deg + NN;                 // [NN+1]
    int* csr    = offp + NN + 1;            // [ETOT]
    int* gstart = csr + ETOT;               // [NG+1]

    // ---- CSR build (shared by both layers) + graph bounds ----
    (void)hipMemsetAsync(deg, 0, NN * sizeof(int), stream);
    csr_hist<<<(ETOT + 255) / 256, 256, 0, stream>>>(dst, deg);
    scan_deg<<<1, 1024, 0, stream>>>(deg, offp);
    (void)hipMemsetAsync(deg, 0, NN * sizeof(int), stream);   // reuse as cursor
    csr_fill<<<(ETOT + 255) / 256, 256, 0, stream>>>(src, dst, offp, deg, csr);
    graph_bounds<<<1, 128, 0, stream>>>(batch, gstart);

    // ---- layer 1 ----
    {
        dim3 g(D1 / 64, (NN + 63) / 64);
        sgemm<<<g, 256, 0, stream>>>(NN, D1, IND, x, W1, Hm1);
    }
    node_scores<H1HEADS, HID1><<<(int)(((long)NN * H1HEADS * 64 + 255) / 256), 256, 0, stream>>>(
        Hm1, a_src1, a_dst1, als1, ald1);
    gat_gather<H1HEADS, HID1, 1><<<(NN + 3) / 4, 256, 0, stream>>>(
        offp, csr, als1, ald1, Hm1, b1, out1);

    // ---- layer 2 ----
    {
        dim3 g(D2 / 64, (NN + 63) / 64);
        sgemm<<<g, 256, 0, stream>>>(NN, D2, D1, out1, W2, Hm2);
    }
    node_scores<1, D2><<<(int)(((long)NN * 64 + 255) / 256), 256, 0, stream>>>(
        Hm2, a_src2, a_dst2, als2, ald2);
    gat_gather<1, D2, 0><<<(NN + 3) / 4, 256, 0, stream>>>(
        offp, csr, als2, ald2, Hm2, b2, out2);

    // ---- pool (atomic-free) ----
    pool_graph<<<NG, 512, 0, stream>>>(out2, gstart, out);
}

// Round 5
// 457.916 us; speedup vs baseline: 9.3463x; 1.2081x over previous
//
#include <hip/hip_runtime.h>
#include <math.h>

#define NN 50000
#define NE 800000
#define ETOT (NE + NN)
#define NG 64
#define IND 128
#define HID1 64
#define H1HEADS 4
#define D1 256      // H1HEADS*HID1
#define D2 128      // OUT_DIM
#define NEG 0.2f

__device__ __forceinline__ unsigned short bf16rne(float f) {
    unsigned u = __float_as_uint(f);
    u = (u + 0x7FFFu + ((u >> 16) & 1u)) >> 16;
    return (unsigned short)u;
}
__device__ __forceinline__ float bf2f(unsigned short u) {
    return __uint_as_float(((unsigned)u) << 16);
}

// -------- SGEMM: C[M,N](bf16) = A[M,K](f32) @ B[K,N](f32), N%64==0, K%16==0 --
__global__ __launch_bounds__(256) void sgemm_bf16out(int M, int N, int K,
                                                     const float* __restrict__ A,
                                                     const float* __restrict__ B,
                                                     unsigned short* __restrict__ C) {
    __shared__ float As[16][65];
    __shared__ float Bs[16][64];
    const int tid = threadIdx.x;
    const int brow = blockIdx.y * 64, bcol = blockIdx.x * 64;
    const int tr = (tid >> 4) << 2;
    const int tc = (tid & 15) << 2;
    float acc[4][4] = {};
    for (int k0 = 0; k0 < K; k0 += 16) {
        #pragma unroll
        for (int i = tid; i < 64 * 16; i += 256) {
            int r = i >> 4, c = i & 15;
            int gr = brow + r;
            As[c][r] = (gr < M) ? A[(long)gr * K + k0 + c] : 0.f;
        }
        #pragma unroll
        for (int i = tid; i < 16 * 64; i += 256) {
            int r = i >> 6, c = i & 63;
            Bs[r][c] = B[(long)(k0 + r) * N + bcol + c];
        }
        __syncthreads();
        #pragma unroll
        for (int kk = 0; kk < 16; ++kk) {
            float a[4], b[4];
            #pragma unroll
            for (int i = 0; i < 4; ++i) a[i] = As[kk][tr + i];
            #pragma unroll
            for (int j = 0; j < 4; ++j) b[j] = Bs[kk][tc + j];
            #pragma unroll
            for (int i = 0; i < 4; ++i)
                #pragma unroll
                for (int j = 0; j < 4; ++j)
                    acc[i][j] += a[i] * b[j];
        }
        __syncthreads();
    }
    #pragma unroll
    for (int i = 0; i < 4; ++i) {
        int r = brow + tr + i;
        if (r < M) {
            ushort4 pk;
            pk.x = bf16rne(acc[i][0]); pk.y = bf16rne(acc[i][1]);
            pk.z = bf16rne(acc[i][2]); pk.w = bf16rne(acc[i][3]);
            *reinterpret_cast<ushort4*>(&C[(long)r * N + bcol + tc]) = pk;
        }
    }
}

// --------------- per-(node,head) attention score dots (bf16 H) ---------------
template<int H, int C>
__global__ __launch_bounds__(256) void node_scores(const unsigned short* __restrict__ Hb,
                                                   const float* __restrict__ a_s,
                                                   const float* __restrict__ a_d,
                                                   float* __restrict__ al_s,
                                                   float* __restrict__ al_d) {
    long gtid = (long)blockIdx.x * blockDim.x + threadIdx.x;
    long wave = gtid >> 6;
    int lane = threadIdx.x & 63;
    int n = (int)(wave / H), h = (int)(wave % H);
    if (n >= NN) return;
    float ss = 0.f, sd = 0.f;
    const unsigned short* row = Hb + (long)n * (H * C) + h * C;
    #pragma unroll
    for (int c = lane; c < C; c += 64) {
        float v = bf2f(row[c]);
        ss += v * a_s[h * C + c];
        sd += v * a_d[h * C + c];
    }
    #pragma unroll
    for (int off = 32; off > 0; off >>= 1) {
        ss += __shfl_down(ss, off);
        sd += __shfl_down(sd, off);
    }
    if (lane == 0) { al_s[wave] = ss; al_d[wave] = sd; }
}

// --------------- CSR build ---------------------------------------------------
__global__ __launch_bounds__(256) void csr_hist(const int* __restrict__ dst,
                                                int* __restrict__ deg) {
    int i = blockIdx.x * 256 + threadIdx.x;
    if (i >= ETOT) return;
    int d = (i < NE) ? dst[i] : (i - NE);
    atomicAdd(&deg[d], 1);
}

__global__ __launch_bounds__(1024) void scan_deg(const int* __restrict__ deg,
                                                 int* __restrict__ offp) {
    __shared__ int wsum[16];
    __shared__ int carry_s;
    const int tid = threadIdx.x, lane = tid & 63, w = tid >> 6;
    if (tid == 0) carry_s = 0;
    __syncthreads();
    for (int base = 0; base < NN; base += 1024) {
        int i = base + tid;
        int v = (i < NN) ? deg[i] : 0;
        int s = v;
        #pragma unroll
        for (int o = 1; o < 64; o <<= 1) {
            int t = __shfl_up(s, o);
            if (lane >= o) s += t;
        }
        if (lane == 63) wsum[w] = s;
        __syncthreads();
        if (w == 0 && lane < 16) {
            int t = wsum[lane];
            #pragma unroll
            for (int o = 1; o < 16; o <<= 1) {
                int u = __shfl_up(t, o, 16);
                if ((lane & 15) >= o) t += u;
            }
            wsum[lane] = t;
        }
        __syncthreads();
        int wave_off = (w > 0) ? wsum[w - 1] : 0;
        int carry = carry_s;
        if (i < NN) offp[i] = carry + wave_off + (s - v);
        __syncthreads();
        if (tid == 1023) carry_s = carry + wsum[15];
        __syncthreads();
    }
    if (tid == 0) offp[NN] = carry_s;
}

__global__ __launch_bounds__(256) void csr_fill(const int* __restrict__ src,
                                                const int* __restrict__ dst,
                                                const int* __restrict__ offp,
                                                int* __restrict__ cur,
                                                int* __restrict__ csr) {
    int i = blockIdx.x * 256 + threadIdx.x;
    if (i >= ETOT) return;
    int s = (i < NE) ? src[i] : (i - NE);
    int d = (i < NE) ? dst[i] : (i - NE);
    int slot = atomicAdd(&cur[d], 1);
    csr[offp[d] + slot] = s;
}

// --------------- fused softmax + aggregate gather (bf16 H rows) --------------
// one wave per dst node; lanes own D/64 consecutive channels; online softmax
template<int H, int C, int RELU>
__global__ __launch_bounds__(256) void gat_gather(const int* __restrict__ offp,
                                                  const int* __restrict__ csr,
                                                  const float* __restrict__ als,
                                                  const float* __restrict__ ald,
                                                  const unsigned short* __restrict__ Hb,
                                                  const float* __restrict__ bias,
                                                  float* __restrict__ outp) {
    constexpr int D = H * C;
    constexpr int VPL = D / 64;
    __shared__ float sW[4][64][H];
    __shared__ int   sS[4][64];
    const int lane = threadIdx.x & 63;
    const int w = threadIdx.x >> 6;
    const int n = blockIdx.x * 4 + w;
    if (n >= NN) return;
    const int h = (lane * VPL) / C;   // head owning this lane's channels

    float aldv[H], m[H], den[H];
    #pragma unroll
    for (int hh = 0; hh < H; ++hh) {
        aldv[hh] = ald[(long)n * H + hh];
        m[hh] = -INFINITY;
        den[hh] = 0.f;
    }
    float acc[VPL] = {};

    const int e0 = offp[n], e1 = offp[n + 1];
    for (int base = e0; base < e1; base += 64) {
        const int cntc = min(64, e1 - base);
        const bool valid = lane < cntc;
        const int s_l = valid ? csr[base + lane] : 0;
        float scv[H];
        #pragma unroll
        for (int hh = 0; hh < H; ++hh) {
            float x = als[(long)s_l * H + hh] + aldv[hh];
            x = (x >= 0.f) ? x : NEG * x;
            x = valid ? x : -INFINITY;
            float cm = x;
            #pragma unroll
            for (int o = 32; o > 0; o >>= 1) cm = fmaxf(cm, __shfl_xor(cm, o));
            float nm = fmaxf(m[hh], cm);
            scv[hh] = expf(m[hh] - nm);          // 0 on first chunk
            float wl = valid ? expf(x - nm) : 0.f;
            float ws_ = wl;
            #pragma unroll
            for (int o = 32; o > 0; o >>= 1) ws_ += __shfl_xor(ws_, o);
            den[hh] = den[hh] * scv[hh] + ws_;
            m[hh] = nm;
            sW[w][lane][hh] = wl;                // invalid lanes wrote 0
        }
        sS[w][lane] = s_l;                       // invalid lanes: node 0 (weight 0)
        float sc_own = scv[0];
        #pragma unroll
        for (int i = 1; i < H; ++i) sc_own = (h == i) ? scv[i] : sc_own;
        #pragma unroll
        for (int k = 0; k < VPL; ++k) acc[k] *= sc_own;

        // 4-edge unrolled accumulate: 4 independent row loads in flight
        const int cnt4 = (cntc + 3) & ~3;
        for (int j0 = 0; j0 < cnt4; j0 += 4) {
            int se0 = sS[w][j0 + 0], se1 = sS[w][j0 + 1];
            int se2 = sS[w][j0 + 2], se3 = sS[w][j0 + 3];
            float w0 = sW[w][j0 + 0][h], w1 = sW[w][j0 + 1][h];
            float w2 = sW[w][j0 + 2][h], w3 = sW[w][j0 + 3][h];
            if constexpr (VPL == 4) {
                ushort4 a0 = *reinterpret_cast<const ushort4*>(Hb + (long)se0 * D + lane * 4);
                ushort4 a1 = *reinterpret_cast<const ushort4*>(Hb + (long)se1 * D + lane * 4);
                ushort4 a2 = *reinterpret_cast<const ushort4*>(Hb + (long)se2 * D + lane * 4);
                ushort4 a3 = *reinterpret_cast<const ushort4*>(Hb + (long)se3 * D + lane * 4);
                acc[0] += w0 * bf2f(a0.x); acc[1] += w0 * bf2f(a0.y);
                acc[2] += w0 * bf2f(a0.z); acc[3] += w0 * bf2f(a0.w);
                acc[0] += w1 * bf2f(a1.x); acc[1] += w1 * bf2f(a1.y);
                acc[2] += w1 * bf2f(a1.z); acc[3] += w1 * bf2f(a1.w);
                acc[0] += w2 * bf2f(a2.x); acc[1] += w2 * bf2f(a2.y);
                acc[2] += w2 * bf2f(a2.z); acc[3] += w2 * bf2f(a2.w);
                acc[0] += w3 * bf2f(a3.x); acc[1] += w3 * bf2f(a3.y);
                acc[2] += w3 * bf2f(a3.z); acc[3] += w3 * bf2f(a3.w);
            } else {
                ushort2 a0 = *reinterpret_cast<const ushort2*>(Hb + (long)se0 * D + lane * 2);
                ushort2 a1 = *reinterpret_cast<const ushort2*>(Hb + (long)se1 * D + lane * 2);
                ushort2 a2 = *reinterpret_cast<const ushort2*>(Hb + (long)se2 * D + lane * 2);
                ushort2 a3 = *reinterpret_cast<const ushort2*>(Hb + (long)se3 * D + lane * 2);
                acc[0] += w0 * bf2f(a0.x); acc[1] += w0 * bf2f(a0.y);
                acc[0] += w1 * bf2f(a1.x); acc[1] += w1 * bf2f(a1.y);
                acc[0] += w2 * bf2f(a2.x); acc[1] += w2 * bf2f(a2.y);
                acc[0] += w3 * bf2f(a3.x); acc[1] += w3 * bf2f(a3.y);
            }
        }
    }
    float dn = den[0];
    #pragma unroll
    for (int i = 1; i < H; ++i) dn = (h == i) ? den[i] : dn;
    float inv = 1.f / dn;
    #pragma unroll
    for (int k = 0; k < VPL; ++k) {
        float v = acc[k] * inv + bias[lane * VPL + k];
        if (RELU) v = fmaxf(v, 0.f);
        outp[(long)n * D + lane * VPL + k] = v;
    }
}

// --------------- pooling (atomic-free: batch is sorted) ----------------------
__global__ __launch_bounds__(128) void graph_bounds(const int* __restrict__ batch,
                                                    int* __restrict__ gstart) {
    int g = threadIdx.x;
    if (g > NG) return;
    int lo = 0, hi = NN;
    while (lo < hi) {
        int mid = (lo + hi) >> 1;
        if (batch[mid] < g) lo = mid + 1; else hi = mid;
    }
    gstart[g] = lo;
}

__global__ __launch_bounds__(512) void pool_graph(const float* __restrict__ out2,
                                                  const int* __restrict__ gstart,
                                                  float* __restrict__ out) {
    __shared__ float part[4][128];
    const int g = blockIdx.x;
    const int ch = threadIdx.x & 127;
    const int q = threadIdx.x >> 7;
    const int s = gstart[g], e = gstart[g + 1];
    float acc = 0.f;
    for (int r = s + q; r < e; r += 4)
        acc += out2[(long)r * D2 + ch];
    part[q][ch] = acc;
    __syncthreads();
    if (q == 0) {
        float v = part[0][ch] + part[1][ch] + part[2][ch] + part[3][ch];
        out[g * D2 + ch] = v / fmaxf((float)(e - s), 1.f);
    }
}

extern "C" void kernel_launch(void* const* d_in, const int* in_sizes, int n_in,
                              void* d_out, int out_size, void* d_ws, size_t ws_size,
                              hipStream_t stream) {
    const float* x      = (const float*)d_in[0];
    const int*   src    = (const int*)d_in[1];
    const int*   dst    = (const int*)d_in[2];
    const int*   batch  = (const int*)d_in[3];
    const float* W1     = (const float*)d_in[4];
    const float* a_src1 = (const float*)d_in[5];
    const float* a_dst1 = (const float*)d_in[6];
    const float* b1     = (const float*)d_in[7];
    const float* W2     = (const float*)d_in[8];
    const float* a_src2 = (const float*)d_in[9];
    const float* a_dst2 = (const float*)d_in[10];
    const float* b2     = (const float*)d_in[11];
    float* out = (float*)d_out;

    // workspace layout (~30.2M float-equiv = 121 MB)
    float* ws   = (float*)d_ws;
    float* out1 = ws;                          // [NN*256] f32
    float* out2 = out1 + (long)NN * D1;        // [NN*128] f32
    float* als1 = out2 + (long)NN * D2;        // [NN*4]
    float* ald1 = als1 + (long)NN * H1HEADS;   // [NN*4]
    float* als2 = als1;                        // [NN] alias (layer1 scores dead)
    float* ald2 = als1 + NN;                   // [NN]
    unsigned short* Hb1 = (unsigned short*)(ald1 + (long)NN * H1HEADS); // [NN*256] bf16
    unsigned short* Hb2 = Hb1 + (long)NN * D1; // [NN*128] bf16
    int* deg    = (int*)(Hb2 + (long)NN * D2); // [NN] (also fill cursor)
    int* offp   = deg + NN;                    // [NN+1]
    int* csr    = offp + NN + 1;               // [ETOT]
    int* gstart = csr + ETOT;                  // [NG+1]

    // ---- CSR build (shared by both layers) + graph bounds ----
    (void)hipMemsetAsync(deg, 0, NN * sizeof(int), stream);
    csr_hist<<<(ETOT + 255) / 256, 256, 0, stream>>>(dst, deg);
    scan_deg<<<1, 1024, 0, stream>>>(deg, offp);
    (void)hipMemsetAsync(deg, 0, NN * sizeof(int), stream);
    csr_fill<<<(ETOT + 255) / 256, 256, 0, stream>>>(src, dst, offp, deg, csr);
    graph_bounds<<<1, 128, 0, stream>>>(batch, gstart);

    // ---- layer 1 ----
    {
        dim3 g(D1 / 64, (NN + 63) / 64);
        sgemm_bf16out<<<g, 256, 0, stream>>>(NN, D1, IND, x, W1, Hb1);
    }
    node_scores<H1HEADS, HID1><<<(int)(((long)NN * H1HEADS * 64 + 255) / 256), 256, 0, stream>>>(
        Hb1, a_src1, a_dst1, als1, ald1);
    gat_gather<H1HEADS, HID1, 1><<<(NN + 3) / 4, 256, 0, stream>>>(
        offp, csr, als1, ald1, Hb1, b1, out1);

    // ---- layer 2 ----
    {
        dim3 g(D2 / 64, (NN + 63) / 64);
        sgemm_bf16out<<<g, 256, 0, stream>>>(NN, D2, D1, out1, W2, Hb2);
    }
    node_scores<1, D2><<<(int)(((long)NN * 64 + 255) / 256), 256, 0, stream>>>(
        Hb2, a_src2, a_dst2, als2, ald2);
    gat_gather<1, D2, 0><<<(NN + 3) / 4, 256, 0, stream>>>(
        offp, csr, als2, ald2, Hb2, b2, out2);

    // ---- pool (atomic-free) ----
    pool_graph<<<NG, 512, 0, stream>>>(out2, gstart, out);
}

// Round 6
// 396.015 us; speedup vs baseline: 10.8072x; 1.1563x over previous
//
#include <hip/hip_runtime.h>
#include <math.h>

#define NN 50000
#define NE 800000
#define ETOT (NE + NN)
#define NG 64
#define IND 128
#define HID1 64
#define H1HEADS 4
#define D1 256      // H1HEADS*HID1
#define D2 128      // OUT_DIM
#define NEG 0.2f

typedef __attribute__((ext_vector_type(8))) short bf16x8;
typedef __attribute__((ext_vector_type(4))) float f32x4;

__device__ __forceinline__ unsigned short bf16rne(float f) {
    unsigned u = __float_as_uint(f);
    u = (u + 0x7FFFu + ((u >> 16) & 1u)) >> 16;
    return (unsigned short)u;
}
__device__ __forceinline__ float bf2f(unsigned short u) {
    return __uint_as_float(((unsigned)u) << 16);
}

// ---------------- prep: f32 -> bf16 convert / transpose ----------------------
__global__ __launch_bounds__(256) void conv_bf16(const float* __restrict__ in,
                                                 unsigned short* __restrict__ outp,
                                                 long n4) {
    long i = (long)blockIdx.x * 256 + threadIdx.x;
    if (i >= n4) return;
    float4 v = reinterpret_cast<const float4*>(in)[i];
    ushort4 p;
    p.x = bf16rne(v.x); p.y = bf16rne(v.y); p.z = bf16rne(v.z); p.w = bf16rne(v.w);
    reinterpret_cast<ushort4*>(outp)[i] = p;
}

// in [R][Cc] f32 -> out [Cc][R] bf16
__global__ __launch_bounds__(256) void transpose_bf16(const float* __restrict__ in,
                                                      unsigned short* __restrict__ outp,
                                                      int R, int Cc) {
    int i = blockIdx.x * 256 + threadIdx.x;
    if (i >= R * Cc) return;
    int c_ = i / R, r_ = i % R;
    outp[i] = bf16rne(in[(long)r_ * Cc + c_]);
}

// ------ MFMA GEMM: A[M,K] bf16 row-major, Bt[N,K] bf16 row-major, C[M,N] bf16
// block = 4 waves, each wave: 16 rows x all N; acc in f32x4 frags
template<int K, int N>
__global__ __launch_bounds__(256) void mfma_gemm(int M,
                                                 const unsigned short* __restrict__ A,
                                                 const unsigned short* __restrict__ Bt,
                                                 unsigned short* __restrict__ C) {
    constexpr int NT = N / 16;
    const int w = threadIdx.x >> 6, l = threadIdx.x & 63;
    const int brow = blockIdx.x * 64 + w * 16;
    const int lr = l & 15, lk = (l >> 4) * 8;
    const int ar = min(brow + lr, M - 1);
    const unsigned short* arow = A + (long)ar * K + lk;
    f32x4 acc[NT] = {};
    #pragma unroll
    for (int k0 = 0; k0 < K; k0 += 32) {
        bf16x8 af = *reinterpret_cast<const bf16x8*>(arow + k0);
        #pragma unroll
        for (int n = 0; n < NT; ++n) {
            bf16x8 bfv = *reinterpret_cast<const bf16x8*>(Bt + (long)(n * 16 + lr) * K + lk + k0);
            acc[n] = __builtin_amdgcn_mfma_f32_16x16x32_bf16(af, bfv, acc[n], 0, 0, 0);
        }
    }
    // C/D layout: col = lane&15 (N), row = (lane>>4)*4 + j (M)
    const int orow = brow + (l >> 4) * 4;
    #pragma unroll
    for (int n = 0; n < NT; ++n) {
        #pragma unroll
        for (int j = 0; j < 4; ++j) {
            int r = orow + j;
            if (r < M) C[(long)r * N + n * 16 + lr] = bf16rne(acc[n][j]);
        }
    }
}

// --------------- per-node attention score dots (bf16 H, vectorized) ----------
// wave per node; lane owns VPL consecutive channels; group-reduce per head
template<int H, int C>
__global__ __launch_bounds__(256) void node_scores(const unsigned short* __restrict__ Hb,
                                                   const float* __restrict__ a_s,
                                                   const float* __restrict__ a_d,
                                                   float* __restrict__ al_s,
                                                   float* __restrict__ al_d) {
    constexpr int D = H * C;
    constexpr int VPL = D / 64;      // 4 (layer1) or 2 (layer2)
    constexpr int GRP = 64 / H;      // lanes per head group
    const int lane = threadIdx.x & 63;
    const int n = blockIdx.x * 4 + (threadIdx.x >> 6);
    if (n >= NN) return;
    const int ch0 = lane * VPL;
    float ss = 0.f, sd = 0.f;
    #pragma unroll
    for (int k = 0; k < VPL; ++k) {
        float v = bf2f(Hb[(long)n * D + ch0 + k]);
        ss += v * a_s[ch0 + k];
        sd += v * a_d[ch0 + k];
    }
    #pragma unroll
    for (int o = GRP / 2; o > 0; o >>= 1) {
        ss += __shfl_xor(ss, o);
        sd += __shfl_xor(sd, o);
    }
    if ((lane & (GRP - 1)) == 0) {
        int h = lane / GRP;
        al_s[(long)n * H + h] = ss;
        al_d[(long)n * H + h] = sd;
    }
}

// --------------- CSR build ---------------------------------------------------
__global__ __launch_bounds__(256) void csr_hist(const int* __restrict__ dst,
                                                int* __restrict__ deg) {
    int i = blockIdx.x * 256 + threadIdx.x;
    if (i >= ETOT) return;
    int d = (i < NE) ? dst[i] : (i - NE);
    atomicAdd(&deg[d], 1);
}

__global__ __launch_bounds__(1024) void scan_deg(const int* __restrict__ deg,
                                                 int* __restrict__ offp) {
    __shared__ int wsum[16];
    __shared__ int carry_s;
    const int tid = threadIdx.x, lane = tid & 63, w = tid >> 6;
    if (tid == 0) carry_s = 0;
    __syncthreads();
    for (int base = 0; base < NN; base += 1024) {
        int i = base + tid;
        int v = (i < NN) ? deg[i] : 0;
        int s = v;
        #pragma unroll
        for (int o = 1; o < 64; o <<= 1) {
            int t = __shfl_up(s, o);
            if (lane >= o) s += t;
        }
        if (lane == 63) wsum[w] = s;
        __syncthreads();
        if (w == 0 && lane < 16) {
            int t = wsum[lane];
            #pragma unroll
            for (int o = 1; o < 16; o <<= 1) {
                int u = __shfl_up(t, o, 16);
                if ((lane & 15) >= o) t += u;
            }
            wsum[lane] = t;
        }
        __syncthreads();
        int wave_off = (w > 0) ? wsum[w - 1] : 0;
        int carry = carry_s;
        if (i < NN) offp[i] = carry + wave_off + (s - v);
        __syncthreads();
        if (tid == 1023) carry_s = carry + wsum[15];
        __syncthreads();
    }
    if (tid == 0) offp[NN] = carry_s;
}

__global__ __launch_bounds__(256) void csr_fill(const int* __restrict__ src,
                                                const int* __restrict__ dst,
                                                const int* __restrict__ offp,
                                                int* __restrict__ cur,
                                                int* __restrict__ csr) {
    int i = blockIdx.x * 256 + threadIdx.x;
    if (i >= ETOT) return;
    int s = (i < NE) ? src[i] : (i - NE);
    int d = (i < NE) ? dst[i] : (i - NE);
    int slot = atomicAdd(&cur[d], 1);
    csr[offp[d] + slot] = s;
}

// --------------- fused softmax + aggregate gather (max-free) -----------------
// softmax is shift-invariant; scores O(1) so exp() is f32-safe without max-sub.
// den accumulates inside the j-loop (every lane reads every weight) -> 0 shfl.
template<int H, int C, int RELU, int OUTBF>
__global__ __launch_bounds__(256) void gat_gather(const int* __restrict__ offp,
                                                  const int* __restrict__ csr,
                                                  const float* __restrict__ als,
                                                  const float* __restrict__ ald,
                                                  const unsigned short* __restrict__ Hb,
                                                  const float* __restrict__ bias,
                                                  void* __restrict__ outp_) {
    constexpr int D = H * C;
    constexpr int VPL = D / 64;
    __shared__ float sW[4][64][H];
    __shared__ int   sS[4][64];
    const int lane = threadIdx.x & 63;
    const int w = threadIdx.x >> 6;
    const int n = blockIdx.x * 4 + w;
    if (n >= NN) return;
    const int h = (lane * VPL) / C;

    float aldv[H];
    #pragma unroll
    for (int hh = 0; hh < H; ++hh) aldv[hh] = ald[(long)n * H + hh];

    float acc[VPL] = {};
    float den = 0.f;

    const int e0 = offp[n], e1 = offp[n + 1];
    for (int base = e0; base < e1; base += 64) {
        const int cntc = min(64, e1 - base);
        const bool valid = lane < cntc;
        const int s_l = valid ? csr[base + lane] : 0;
        if constexpr (H == 4) {
            float4 a4 = *reinterpret_cast<const float4*>(als + (long)s_l * 4);
            float xs[4] = {a4.x, a4.y, a4.z, a4.w};
            #pragma unroll
            for (int hh = 0; hh < 4; ++hh) {
                float x = xs[hh] + aldv[hh];
                x = (x >= 0.f) ? x : NEG * x;
                sW[w][lane][hh] = valid ? expf(x) : 0.f;
            }
        } else {
            float x = als[s_l] + aldv[0];
            x = (x >= 0.f) ? x : NEG * x;
            sW[w][lane][0] = valid ? expf(x) : 0.f;
        }
        sS[w][lane] = s_l;

        const int cnt4 = (cntc + 3) & ~3;
        for (int j0 = 0; j0 < cnt4; j0 += 4) {
            int se0 = sS[w][j0 + 0], se1 = sS[w][j0 + 1];
            int se2 = sS[w][j0 + 2], se3 = sS[w][j0 + 3];
            float w0 = sW[w][j0 + 0][h], w1 = sW[w][j0 + 1][h];
            float w2 = sW[w][j0 + 2][h], w3 = sW[w][j0 + 3][h];
            den += (w0 + w1) + (w2 + w3);
            if constexpr (VPL == 4) {
                ushort4 a0 = *reinterpret_cast<const ushort4*>(Hb + (long)se0 * D + lane * 4);
                ushort4 a1 = *reinterpret_cast<const ushort4*>(Hb + (long)se1 * D + lane * 4);
                ushort4 a2 = *reinterpret_cast<const ushort4*>(Hb + (long)se2 * D + lane * 4);
                ushort4 a3 = *reinterpret_cast<const ushort4*>(Hb + (long)se3 * D + lane * 4);
                acc[0] += w0 * bf2f(a0.x); acc[1] += w0 * bf2f(a0.y);
                acc[2] += w0 * bf2f(a0.z); acc[3] += w0 * bf2f(a0.w);
                acc[0] += w1 * bf2f(a1.x); acc[1] += w1 * bf2f(a1.y);
                acc[2] += w1 * bf2f(a1.z); acc[3] += w1 * bf2f(a1.w);
                acc[0] += w2 * bf2f(a2.x); acc[1] += w2 * bf2f(a2.y);
                acc[2] += w2 * bf2f(a2.z); acc[3] += w2 * bf2f(a2.w);
                acc[0] += w3 * bf2f(a3.x); acc[1] += w3 * bf2f(a3.y);
                acc[2] += w3 * bf2f(a3.z); acc[3] += w3 * bf2f(a3.w);
            } else {
                ushort2 a0 = *reinterpret_cast<const ushort2*>(Hb + (long)se0 * D + lane * 2);
                ushort2 a1 = *reinterpret_cast<const ushort2*>(Hb + (long)se1 * D + lane * 2);
                ushort2 a2 = *reinterpret_cast<const ushort2*>(Hb + (long)se2 * D + lane * 2);
                ushort2 a3 = *reinterpret_cast<const ushort2*>(Hb + (long)se3 * D + lane * 2);
                acc[0] += w0 * bf2f(a0.x); acc[1] += w0 * bf2f(a0.y);
                acc[0] += w1 * bf2f(a1.x); acc[1] += w1 * bf2f(a1.y);
                acc[0] += w2 * bf2f(a2.x); acc[1] += w2 * bf2f(a2.y);
                acc[0] += w3 * bf2f(a3.x); acc[1] += w3 * bf2f(a3.y);
            }
        }
    }
    float inv = 1.f / den;   // self-loop guarantees den > 0
    float v[VPL];
    #pragma unroll
    for (int k = 0; k < VPL; ++k) {
        v[k] = acc[k] * inv + bias[lane * VPL + k];
        if (RELU) v[k] = fmaxf(v[k], 0.f);
    }
    if constexpr (OUTBF) {
        unsigned short* o = (unsigned short*)outp_;
        if constexpr (VPL == 4) {
            ushort4 p; p.x = bf16rne(v[0]); p.y = bf16rne(v[1]);
            p.z = bf16rne(v[2]); p.w = bf16rne(v[3]);
            *reinterpret_cast<ushort4*>(o + (long)n * D + lane * 4) = p;
        } else {
            ushort2 p; p.x = bf16rne(v[0]); p.y = bf16rne(v[1]);
            *reinterpret_cast<ushort2*>(o + (long)n * D + lane * 2) = p;
        }
    } else {
        float* o = (float*)outp_;
        if constexpr (VPL == 4) {
            float4 p = {v[0], v[1], v[2], v[3]};
            *reinterpret_cast<float4*>(o + (long)n * D + lane * 4) = p;
        } else {
            float2 p = {v[0], v[1]};
            *reinterpret_cast<float2*>(o + (long)n * D + lane * 2) = p;
        }
    }
}

// --------------- pooling (atomic-free: batch is sorted) ----------------------
__global__ __launch_bounds__(128) void graph_bounds(const int* __restrict__ batch,
                                                    int* __restrict__ gstart) {
    int g = threadIdx.x;
    if (g > NG) return;
    int lo = 0, hi = NN;
    while (lo < hi) {
        int mid = (lo + hi) >> 1;
        if (batch[mid] < g) lo = mid + 1; else hi = mid;
    }
    gstart[g] = lo;
}

__global__ __launch_bounds__(512) void pool_graph(const float* __restrict__ out2,
                                                  const int* __restrict__ gstart,
                                                  float* __restrict__ out) {
    __shared__ float part[4][128];
    const int g = blockIdx.x;
    const int ch = threadIdx.x & 127;
    const int q = threadIdx.x >> 7;
    const int s = gstart[g], e = gstart[g + 1];
    float acc = 0.f;
    for (int r = s + q; r < e; r += 4)
        acc += out2[(long)r * D2 + ch];
    part[q][ch] = acc;
    __syncthreads();
    if (q == 0) {
        float v = part[0][ch] + part[1][ch] + part[2][ch] + part[3][ch];
        out[g * D2 + ch] = v / fmaxf((float)(e - s), 1.f);
    }
}

extern "C" void kernel_launch(void* const* d_in, const int* in_sizes, int n_in,
                              void* d_out, int out_size, void* d_ws, size_t ws_size,
                              hipStream_t stream) {
    const float* x      = (const float*)d_in[0];
    const int*   src    = (const int*)d_in[1];
    const int*   dst    = (const int*)d_in[2];
    const int*   batch  = (const int*)d_in[3];
    const float* W1     = (const float*)d_in[4];
    const float* a_src1 = (const float*)d_in[5];
    const float* a_dst1 = (const float*)d_in[6];
    const float* b1     = (const float*)d_in[7];
    const float* W2     = (const float*)d_in[8];
    const float* a_src2 = (const float*)d_in[9];
    const float* a_dst2 = (const float*)d_in[10];
    const float* b2     = (const float*)d_in[11];
    float* out = (float*)d_out;

    // workspace layout (~108 MB)
    float* ws   = (float*)d_ws;
    float* out2 = ws;                            // [NN*128] f32
    float* als1 = out2 + (long)NN * D2;          // [NN*4]
    float* ald1 = als1 + (long)NN * H1HEADS;     // [NN*4]
    float* als2 = als1;                          // [NN] alias (layer1 dead then)
    float* ald2 = als1 + NN;                     // [NN]
    unsigned short* xb    = (unsigned short*)(ald1 + (long)NN * H1HEADS); // [NN*128]
    unsigned short* Hb1   = xb + (long)NN * IND;   // [NN*256]
    unsigned short* out1b = Hb1 + (long)NN * D1;   // [NN*256]
    unsigned short* Hb2   = out1b + (long)NN * D1; // [NN*128]
    unsigned short* W1t   = Hb2 + (long)NN * D2;   // [256*128]
    unsigned short* W2t   = W1t + D1 * IND;        // [128*256]
    int* deg    = (int*)(W2t + D2 * D1);           // [NN]
    int* offp   = deg + NN;                        // [NN+1]
    int* csr    = offp + NN + 1;                   // [ETOT]
    int* gstart = csr + ETOT;                      // [NG+1]

    // ---- prep: conversions + CSR build + graph bounds ----
    conv_bf16<<<(int)(((long)NN * IND / 4 + 255) / 256), 256, 0, stream>>>(x, xb, (long)NN * IND / 4);
    transpose_bf16<<<(IND * D1 + 255) / 256, 256, 0, stream>>>(W1, W1t, IND, D1);
    transpose_bf16<<<(D1 * D2 + 255) / 256, 256, 0, stream>>>(W2, W2t, D1, D2);
    (void)hipMemsetAsync(deg, 0, NN * sizeof(int), stream);
    csr_hist<<<(ETOT + 255) / 256, 256, 0, stream>>>(dst, deg);
    scan_deg<<<1, 1024, 0, stream>>>(deg, offp);
    (void)hipMemsetAsync(deg, 0, NN * sizeof(int), stream);
    csr_fill<<<(ETOT + 255) / 256, 256, 0, stream>>>(src, dst, offp, deg, csr);
    graph_bounds<<<1, 128, 0, stream>>>(batch, gstart);

    // ---- layer 1 ----
    mfma_gemm<IND, D1><<<(NN + 63) / 64, 256, 0, stream>>>(NN, xb, W1t, Hb1);
    node_scores<H1HEADS, HID1><<<(NN + 3) / 4, 256, 0, stream>>>(Hb1, a_src1, a_dst1, als1, ald1);
    gat_gather<H1HEADS, HID1, 1, 1><<<(NN + 3) / 4, 256, 0, stream>>>(
        offp, csr, als1, ald1, Hb1, b1, out1b);

    // ---- layer 2 ----
    mfma_gemm<D1, D2><<<(NN + 63) / 64, 256, 0, stream>>>(NN, out1b, W2t, Hb2);
    node_scores<1, D2><<<(NN + 3) / 4, 256, 0, stream>>>(Hb2, a_src2, a_dst2, als2, ald2);
    gat_gather<1, D2, 0, 0><<<(NN + 3) / 4, 256, 0, stream>>>(
        offp, csr, als2, ald2, Hb2, b2, out2);

    // ---- pool (atomic-free) ----
    pool_graph<<<NG, 512, 0, stream>>>(out2, gstart, out);
}

// Round 7
// 341.499 us; speedup vs baseline: 12.5325x; 1.1596x over previous
//
#include <hip/hip_runtime.h>
#include <math.h>

#define NN 50000
#define NE 800000
#define ETOT (NE + NN)
#define NG 64
#define IND 128
#define HID1 64
#define H1HEADS 4
#define D1 256      // H1HEADS*HID1
#define D2 128      // OUT_DIM
#define NEG 0.2f
#define NB_SCAN 49  // ceil(NN/1024)

typedef __attribute__((ext_vector_type(8))) short bf16x8;
typedef __attribute__((ext_vector_type(4))) float f32x4;

__device__ __forceinline__ unsigned short bf16rne(float f) {
    unsigned u = __float_as_uint(f);
    u = (u + 0x7FFFu + ((u >> 16) & 1u)) >> 16;
    return (unsigned short)u;
}
__device__ __forceinline__ float bf2f(unsigned short u) {
    return __uint_as_float(((unsigned)u) << 16);
}

// ---------------- prep: f32 -> bf16 convert / transpose ----------------------
__global__ __launch_bounds__(256) void conv_bf16(const float* __restrict__ in,
                                                 unsigned short* __restrict__ outp,
                                                 long n4) {
    long i = (long)blockIdx.x * 256 + threadIdx.x;
    if (i >= n4) return;
    float4 v = reinterpret_cast<const float4*>(in)[i];
    ushort4 p;
    p.x = bf16rne(v.x); p.y = bf16rne(v.y); p.z = bf16rne(v.z); p.w = bf16rne(v.w);
    reinterpret_cast<ushort4*>(outp)[i] = p;
}

// in [R][Cc] f32 -> out [Cc][R] bf16
__global__ __launch_bounds__(256) void transpose_bf16(const float* __restrict__ in,
                                                      unsigned short* __restrict__ outp,
                                                      int R, int Cc) {
    int i = blockIdx.x * 256 + threadIdx.x;
    if (i >= R * Cc) return;
    int c_ = i / R, r_ = i % R;
    outp[i] = bf16rne(in[(long)r_ * Cc + c_]);
}

// ------ MFMA GEMM + fused attention-score epilogue ---------------------------
// A[M,K] bf16 row-major, Bt[N,K] bf16 row-major, C[M,N] bf16.
// Each wave: 16 rows x all N. Epilogue computes per-head dots al_s/al_d from
// the f32 accumulators (16-lane xor-reduce), saving the node_scores pass.
template<int K, int N, int H>
__global__ __launch_bounds__(256) void mfma_gemm_sc(int M,
                                                    const unsigned short* __restrict__ A,
                                                    const unsigned short* __restrict__ Bt,
                                                    const float* __restrict__ a_s,
                                                    const float* __restrict__ a_d,
                                                    unsigned short* __restrict__ C,
                                                    float* __restrict__ al_s,
                                                    float* __restrict__ al_d) {
    constexpr int NT = N / 16;
    constexpr int FPH = NT / H;        // frags per head
    const int w = threadIdx.x >> 6, l = threadIdx.x & 63;
    const int brow = blockIdx.x * 64 + w * 16;
    const int lr = l & 15, lk = (l >> 4) * 8;
    const int ar = min(brow + lr, M - 1);
    const unsigned short* arow = A + (long)ar * K + lk;
    f32x4 acc[NT] = {};
    #pragma unroll
    for (int k0 = 0; k0 < K; k0 += 32) {
        bf16x8 af = *reinterpret_cast<const bf16x8*>(arow + k0);
        #pragma unroll
        for (int n = 0; n < NT; ++n) {
            bf16x8 bv = *reinterpret_cast<const bf16x8*>(Bt + (long)(n * 16 + lr) * K + lk + k0);
            acc[n] = __builtin_amdgcn_mfma_f32_16x16x32_bf16(af, bv, acc[n], 0, 0, 0);
        }
    }
    float asv[NT], adv[NT];
    #pragma unroll
    for (int n = 0; n < NT; ++n) { asv[n] = a_s[n * 16 + lr]; adv[n] = a_d[n * 16 + lr]; }
    // C/D layout: col = lane&15, row = (lane>>4)*4 + j
    const int orow = brow + (l >> 4) * 4;
    #pragma unroll
    for (int j = 0; j < 4; ++j) {
        int r = orow + j;
        bool ok = r < M;
        #pragma unroll
        for (int n = 0; n < NT; ++n)
            if (ok) C[(long)r * N + n * 16 + lr] = bf16rne(acc[n][j]);
        #pragma unroll
        for (int h = 0; h < H; ++h) {
            float ss = 0.f, sd = 0.f;
            #pragma unroll
            for (int f = 0; f < FPH; ++f) {
                int n = h * FPH + f;
                ss += acc[n][j] * asv[n];
                sd += acc[n][j] * adv[n];
            }
            #pragma unroll
            for (int o = 8; o > 0; o >>= 1) {
                ss += __shfl_xor(ss, o);
                sd += __shfl_xor(sd, o);
            }
            if (ok && lr == 0) {
                al_s[(long)r * H + h] = ss;
                al_d[(long)r * H + h] = sd;
            }
        }
    }
}

// --------------- CSR build ---------------------------------------------------
__global__ __launch_bounds__(256) void csr_hist(const int* __restrict__ dst,
                                                int* __restrict__ deg) {
    int i = blockIdx.x * 256 + threadIdx.x;
    if (i >= ETOT) return;
    int d = (i < NE) ? dst[i] : (i - NE);
    atomicAdd(&deg[d], 1);
}

// two-level scan: block-local exclusive prefix + block sums
__global__ __launch_bounds__(1024) void scan1(const int* __restrict__ deg,
                                              int* __restrict__ offp,
                                              int* __restrict__ bsum) {
    __shared__ int wsum[16];
    const int tid = threadIdx.x, lane = tid & 63, w = tid >> 6;
    const int i = blockIdx.x * 1024 + tid;
    int v = (i < NN) ? deg[i] : 0;
    int s = v;
    #pragma unroll
    for (int o = 1; o < 64; o <<= 1) {
        int t = __shfl_up(s, o);
        if (lane >= o) s += t;
    }
    if (lane == 63) wsum[w] = s;
    __syncthreads();
    if (w == 0 && lane < 16) {
        int t = wsum[lane];
        #pragma unroll
        for (int o = 1; o < 16; o <<= 1) {
            int u = __shfl_up(t, o, 16);
            if ((lane & 15) >= o) t += u;
        }
        wsum[lane] = t;
    }
    __syncthreads();
    int woff = (w > 0) ? wsum[w - 1] : 0;
    if (i < NN) offp[i] = woff + s - v;
    if (tid == 0) bsum[blockIdx.x] = wsum[15];
}

__global__ __launch_bounds__(64) void scan2(const int* __restrict__ bsum,
                                            int* __restrict__ bpre,
                                            int* __restrict__ offp) {
    int lane = threadIdx.x;
    int v = (lane < NB_SCAN) ? bsum[lane] : 0;
    int s = v;
    #pragma unroll
    for (int o = 1; o < 64; o <<= 1) {
        int t = __shfl_up(s, o);
        if (lane >= o) s += t;
    }
    if (lane < NB_SCAN) bpre[lane] = s - v;
    if (lane == 63) offp[NN] = s;
}

__global__ __launch_bounds__(256) void scan3(int* __restrict__ offp,
                                             const int* __restrict__ bpre) {
    int i = blockIdx.x * 256 + threadIdx.x;
    if (i < NN) offp[i] += bpre[i >> 10];
}

__global__ __launch_bounds__(256) void csr_fill(const int* __restrict__ src,
                                                const int* __restrict__ dst,
                                                const int* __restrict__ offp,
                                                int* __restrict__ cur,
                                                int* __restrict__ csr) {
    int i = blockIdx.x * 256 + threadIdx.x;
    if (i >= ETOT) return;
    int s = (i < NE) ? src[i] : (i - NE);
    int d = (i < NE) ? dst[i] : (i - NE);
    int slot = atomicAdd(&cur[d], 1);
    csr[offp[d] + slot] = s;
}

// --------------- fused softmax + aggregate gather (max-free, 8-deep ILP) -----
template<int H, int C, int RELU, int OUTBF>
__global__ __launch_bounds__(256) void gat_gather(const int* __restrict__ offp,
                                                  const int* __restrict__ csr,
                                                  const float* __restrict__ als,
                                                  const float* __restrict__ ald,
                                                  const unsigned short* __restrict__ Hb,
                                                  const float* __restrict__ bias,
                                                  void* __restrict__ outp_) {
    constexpr int D = H * C;
    constexpr int VPL = D / 64;
    constexpr int HP = (H == 4) ? 5 : 1;   // pad: stride 5 floats, gcd(5,32)=1
    __shared__ float sW[4][64][HP];
    __shared__ int   sS[4][64];
    const int lane = threadIdx.x & 63;
    const int w = threadIdx.x >> 6;
    const int n = blockIdx.x * 4 + w;
    if (n >= NN) return;
    const int h = (lane * VPL) / C;

    float aldv[H];
    #pragma unroll
    for (int hh = 0; hh < H; ++hh) aldv[hh] = ald[(long)n * H + hh];

    float acc[VPL] = {};
    float den = 0.f;

    const int e0 = offp[n], e1 = offp[n + 1];
    for (int base = e0; base < e1; base += 64) {
        const int cntc = min(64, e1 - base);
        const bool valid = lane < cntc;
        const int s_l = valid ? csr[base + lane] : 0;
        if constexpr (H == 4) {
            float4 a4 = *reinterpret_cast<const float4*>(als + (long)s_l * 4);
            float xs[4] = {a4.x, a4.y, a4.z, a4.w};
            #pragma unroll
            for (int hh = 0; hh < 4; ++hh) {
                float x = xs[hh] + aldv[hh];
                x = (x >= 0.f) ? x : NEG * x;
                sW[w][lane][hh] = valid ? expf(x) : 0.f;
            }
        } else {
            float x = als[s_l] + aldv[0];
            x = (x >= 0.f) ? x : NEG * x;
            sW[w][lane][0] = valid ? expf(x) : 0.f;
        }
        sS[w][lane] = s_l;

        int j0 = 0;
        // 8-deep main loop: 8 independent row loads in flight
        for (; j0 + 8 <= cntc; j0 += 8) {
            int se[8]; float we[8];
            #pragma unroll
            for (int t = 0; t < 8; ++t) {
                se[t] = sS[w][j0 + t];
                we[t] = sW[w][j0 + t][h];
            }
            #pragma unroll
            for (int t = 0; t < 8; ++t) den += we[t];
            if constexpr (VPL == 4) {
                ushort4 aa[8];
                #pragma unroll
                for (int t = 0; t < 8; ++t)
                    aa[t] = *reinterpret_cast<const ushort4*>(Hb + (long)se[t] * D + lane * 4);
                #pragma unroll
                for (int t = 0; t < 8; ++t) {
                    acc[0] += we[t] * bf2f(aa[t].x); acc[1] += we[t] * bf2f(aa[t].y);
                    acc[2] += we[t] * bf2f(aa[t].z); acc[3] += we[t] * bf2f(aa[t].w);
                }
            } else {
                ushort2 aa[8];
                #pragma unroll
                for (int t = 0; t < 8; ++t)
                    aa[t] = *reinterpret_cast<const ushort2*>(Hb + (long)se[t] * D + lane * 2);
                #pragma unroll
                for (int t = 0; t < 8; ++t) {
                    acc[0] += we[t] * bf2f(aa[t].x); acc[1] += we[t] * bf2f(aa[t].y);
                }
            }
        }
        // masked 4-wide tail (slots >= cntc hold weight 0 / node 0)
        for (; j0 < cntc; j0 += 4) {
            int se[4]; float we[4];
            #pragma unroll
            for (int t = 0; t < 4; ++t) {
                se[t] = sS[w][j0 + t];
                we[t] = sW[w][j0 + t][h];
            }
            #pragma unroll
            for (int t = 0; t < 4; ++t) den += we[t];
            if constexpr (VPL == 4) {
                ushort4 aa[4];
                #pragma unroll
                for (int t = 0; t < 4; ++t)
                    aa[t] = *reinterpret_cast<const ushort4*>(Hb + (long)se[t] * D + lane * 4);
                #pragma unroll
                for (int t = 0; t < 4; ++t) {
                    acc[0] += we[t] * bf2f(aa[t].x); acc[1] += we[t] * bf2f(aa[t].y);
                    acc[2] += we[t] * bf2f(aa[t].z); acc[3] += we[t] * bf2f(aa[t].w);
                }
            } else {
                ushort2 aa[4];
                #pragma unroll
                for (int t = 0; t < 4; ++t)
                    aa[t] = *reinterpret_cast<const ushort2*>(Hb + (long)se[t] * D + lane * 2);
                #pragma unroll
                for (int t = 0; t < 4; ++t) {
                    acc[0] += we[t] * bf2f(aa[t].x); acc[1] += we[t] * bf2f(aa[t].y);
                }
            }
        }
    }
    float inv = 1.f / den;   // self-loop guarantees den > 0
    float v[VPL];
    #pragma unroll
    for (int k = 0; k < VPL; ++k) {
        v[k] = acc[k] * inv + bias[lane * VPL + k];
        if (RELU) v[k] = fmaxf(v[k], 0.f);
    }
    if constexpr (OUTBF) {
        unsigned short* o = (unsigned short*)outp_;
        if constexpr (VPL == 4) {
            ushort4 p; p.x = bf16rne(v[0]); p.y = bf16rne(v[1]);
            p.z = bf16rne(v[2]); p.w = bf16rne(v[3]);
            *reinterpret_cast<ushort4*>(o + (long)n * D + lane * 4) = p;
        } else {
            ushort2 p; p.x = bf16rne(v[0]); p.y = bf16rne(v[1]);
            *reinterpret_cast<ushort2*>(o + (long)n * D + lane * 2) = p;
        }
    } else {
        float* o = (float*)outp_;
        if constexpr (VPL == 4) {
            float4 p = {v[0], v[1], v[2], v[3]};
            *reinterpret_cast<float4*>(o + (long)n * D + lane * 4) = p;
        } else {
            float2 p = {v[0], v[1]};
            *reinterpret_cast<float2*>(o + (long)n * D + lane * 2) = p;
        }
    }
}

// --------------- pooling (atomic-free: batch is sorted) ----------------------
__global__ __launch_bounds__(128) void graph_bounds(const int* __restrict__ batch,
                                                    int* __restrict__ gstart) {
    int g = threadIdx.x;
    if (g > NG) return;
    int lo = 0, hi = NN;
    while (lo < hi) {
        int mid = (lo + hi) >> 1;
        if (batch[mid] < g) lo = mid + 1; else hi = mid;
    }
    gstart[g] = lo;
}

__global__ __launch_bounds__(512) void pool_graph(const float* __restrict__ out2,
                                                  const int* __restrict__ gstart,
                                                  float* __restrict__ out) {
    __shared__ float part[4][128];
    const int g = blockIdx.x;
    const int ch = threadIdx.x & 127;
    const int q = threadIdx.x >> 7;
    const int s = gstart[g], e = gstart[g + 1];
    float acc = 0.f;
    for (int r = s + q; r < e; r += 4)
        acc += out2[(long)r * D2 + ch];
    part[q][ch] = acc;
    __syncthreads();
    if (q == 0) {
        float v = part[0][ch] + part[1][ch] + part[2][ch] + part[3][ch];
        out[g * D2 + ch] = v / fmaxf((float)(e - s), 1.f);
    }
}

extern "C" void kernel_launch(void* const* d_in, const int* in_sizes, int n_in,
                              void* d_out, int out_size, void* d_ws, size_t ws_size,
                              hipStream_t stream) {
    const float* x      = (const float*)d_in[0];
    const int*   src    = (const int*)d_in[1];
    const int*   dst    = (const int*)d_in[2];
    const int*   batch  = (const int*)d_in[3];
    const float* W1     = (const float*)d_in[4];
    const float* a_src1 = (const float*)d_in[5];
    const float* a_dst1 = (const float*)d_in[6];
    const float* b1     = (const float*)d_in[7];
    const float* W2     = (const float*)d_in[8];
    const float* a_src2 = (const float*)d_in[9];
    const float* a_dst2 = (const float*)d_in[10];
    const float* b2     = (const float*)d_in[11];
    float* out = (float*)d_out;

    // workspace layout (~108 MB)
    float* ws   = (float*)d_ws;
    float* out2 = ws;                            // [NN*128] f32
    float* als1 = out2 + (long)NN * D2;          // [NN*4]
    float* ald1 = als1 + (long)NN * H1HEADS;     // [NN*4]
    float* als2 = als1;                          // [NN] alias (layer1 dead then)
    float* ald2 = als1 + NN;                     // [NN]
    unsigned short* xb    = (unsigned short*)(ald1 + (long)NN * H1HEADS); // [NN*128]
    unsigned short* Hb1   = xb + (long)NN * IND;   // [NN*256]
    unsigned short* out1b = Hb1 + (long)NN * D1;   // [NN*256]
    unsigned short* Hb2   = out1b + (long)NN * D1; // [NN*128]
    unsigned short* W1t   = Hb2 + (long)NN * D2;   // [256*128]
    unsigned short* W2t   = W1t + D1 * IND;        // [128*256]
    int* deg    = (int*)(W2t + D2 * D1);           // [NN] (also fill cursor)
    int* offp   = deg + NN;                        // [NN+1]
    int* csr    = offp + NN + 1;                   // [ETOT]
    int* gstart = csr + ETOT;                      // [NG+1]
    int* bsum   = gstart + NG + 1;                 // [NB_SCAN]
    int* bpre   = bsum + NB_SCAN;                  // [NB_SCAN]

    // ---- prep: conversions + CSR build + graph bounds ----
    conv_bf16<<<(int)(((long)NN * IND / 4 + 255) / 256), 256, 0, stream>>>(x, xb, (long)NN * IND / 4);
    transpose_bf16<<<(IND * D1 + 255) / 256, 256, 0, stream>>>(W1, W1t, IND, D1);
    transpose_bf16<<<(D1 * D2 + 255) / 256, 256, 0, stream>>>(W2, W2t, D1, D2);
    (void)hipMemsetAsync(deg, 0, NN * sizeof(int), stream);
    csr_hist<<<(ETOT + 255) / 256, 256, 0, stream>>>(dst, deg);
    scan1<<<NB_SCAN, 1024, 0, stream>>>(deg, offp, bsum);
    scan2<<<1, 64, 0, stream>>>(bsum, bpre, offp);
    scan3<<<(NN + 255) / 256, 256, 0, stream>>>(offp, bpre);
    (void)hipMemsetAsync(deg, 0, NN * sizeof(int), stream);
    csr_fill<<<(ETOT + 255) / 256, 256, 0, stream>>>(src, dst, offp, deg, csr);
    graph_bounds<<<1, 128, 0, stream>>>(batch, gstart);

    // ---- layer 1 ----
    mfma_gemm_sc<IND, D1, H1HEADS><<<(NN + 63) / 64, 256, 0, stream>>>(
        NN, xb, W1t, a_src1, a_dst1, Hb1, als1, ald1);
    gat_gather<H1HEADS, HID1, 1, 1><<<(NN + 3) / 4, 256, 0, stream>>>(
        offp, csr, als1, ald1, Hb1, b1, out1b);

    // ---- layer 2 ----
    mfma_gemm_sc<D1, D2, 1><<<(NN + 63) / 64, 256, 0, stream>>>(
        NN, out1b, W2t, a_src2, a_dst2, Hb2, als2, ald2);
    gat_gather<1, D2, 0, 0><<<(NN + 3) / 4, 256, 0, stream>>>(
        offp, csr, als2, ald2, Hb2, b2, out2);

    // ---- pool (atomic-free) ----
    pool_graph<<<NG, 512, 0, stream>>>(out2, gstart, out);
}

// Round 8
// 308.113 us; speedup vs baseline: 13.8904x; 1.1084x over previous
//
#include <hip/hip_runtime.h>
#include <math.h>

#define NN 50000
#define NE 800000
#define ETOT (NE + NN)
#define NG 64
#define IND 128
#define HID1 64
#define H1HEADS 4
#define D1 256      // H1HEADS*HID1
#define D2 128      // OUT_DIM
#define NEG 0.2f
#define NB_SCAN 49  // ceil(NN/1024)

typedef __attribute__((ext_vector_type(8))) short bf16x8;
typedef __attribute__((ext_vector_type(4))) float f32x4;

__device__ __forceinline__ unsigned short bf16rne(float f) {
    unsigned u = __float_as_uint(f);
    u = (u + 0x7FFFu + ((u >> 16) & 1u)) >> 16;
    return (unsigned short)u;
}
__device__ __forceinline__ float bf2f(unsigned short u) {
    return __uint_as_float(((unsigned)u) << 16);
}

// ---------------- fused prep: x->bf16, W1^T->bf16, W2^T->bf16, zero deg ------
__global__ __launch_bounds__(256) void prep_all(const float* __restrict__ x,
                                                unsigned short* __restrict__ xb,
                                                const float* __restrict__ W1,
                                                unsigned short* __restrict__ W1t,
                                                const float* __restrict__ W2,
                                                unsigned short* __restrict__ W2t,
                                                int* __restrict__ deg) {
    const long N4 = (long)NN * IND / 4;          // x in float4 groups
    long i = (long)blockIdx.x * 256 + threadIdx.x;
    if (i < N4) {
        float4 v = reinterpret_cast<const float4*>(x)[i];
        ushort4 p;
        p.x = bf16rne(v.x); p.y = bf16rne(v.y); p.z = bf16rne(v.z); p.w = bf16rne(v.w);
        reinterpret_cast<ushort4*>(xb)[i] = p;
    } else if (i < N4 + IND * D1) {
        int j = (int)(i - N4);                   // W1t [D1][IND]
        int c_ = j / IND, r_ = j % IND;
        W1t[j] = bf16rne(W1[(long)r_ * D1 + c_]);
    } else if (i < N4 + IND * D1 + D1 * D2) {
        int j = (int)(i - N4 - IND * D1);        // W2t [D2][D1]
        int c_ = j / D1, r_ = j % D1;
        W2t[j] = bf16rne(W2[(long)r_ * D2 + c_]);
    } else if (i < N4 + IND * D1 + D1 * D2 + NN) {
        deg[i - N4 - IND * D1 - D1 * D2] = 0;
    }
}

// ------ MFMA GEMM + fused attention-score epilogue ---------------------------
// A[M,K] bf16 row-major, Bt[N,K] bf16 row-major, C[M,N] bf16.
// Each wave: 32 rows (2 A-frags share each B-frag) x all N.
template<int K, int N, int H>
__global__ __launch_bounds__(256) void mfma_gemm_sc(int M,
                                                    const unsigned short* __restrict__ A,
                                                    const unsigned short* __restrict__ Bt,
                                                    const float* __restrict__ a_s,
                                                    const float* __restrict__ a_d,
                                                    unsigned short* __restrict__ C,
                                                    float* __restrict__ al_s,
                                                    float* __restrict__ al_d) {
    constexpr int NT = N / 16;
    constexpr int FPH = NT / H;        // frags per head
    const int w = threadIdx.x >> 6, l = threadIdx.x & 63;
    const int brow = blockIdx.x * 128 + w * 32;
    const int lr = l & 15, lk = (l >> 4) * 8;
    const int ar0 = min(brow + lr, M - 1);
    const int ar1 = min(brow + 16 + lr, M - 1);
    const unsigned short* arow0 = A + (long)ar0 * K + lk;
    const unsigned short* arow1 = A + (long)ar1 * K + lk;
    f32x4 acc[2][NT] = {};
    #pragma unroll
    for (int k0 = 0; k0 < K; k0 += 32) {
        bf16x8 af0 = *reinterpret_cast<const bf16x8*>(arow0 + k0);
        bf16x8 af1 = *reinterpret_cast<const bf16x8*>(arow1 + k0);
        #pragma unroll
        for (int n = 0; n < NT; ++n) {
            bf16x8 bv = *reinterpret_cast<const bf16x8*>(Bt + (long)(n * 16 + lr) * K + lk + k0);
            acc[0][n] = __builtin_amdgcn_mfma_f32_16x16x32_bf16(af0, bv, acc[0][n], 0, 0, 0);
            acc[1][n] = __builtin_amdgcn_mfma_f32_16x16x32_bf16(af1, bv, acc[1][n], 0, 0, 0);
        }
    }
    float asv[NT], adv[NT];
    #pragma unroll
    for (int n = 0; n < NT; ++n) { asv[n] = a_s[n * 16 + lr]; adv[n] = a_d[n * 16 + lr]; }
    // C/D layout: col = lane&15, row = (lane>>4)*4 + j
    #pragma unroll
    for (int g = 0; g < 2; ++g) {
        const int orow = brow + g * 16 + (l >> 4) * 4;
        #pragma unroll
        for (int j = 0; j < 4; ++j) {
            int r = orow + j;
            bool ok = r < M;
            #pragma unroll
            for (int n = 0; n < NT; ++n)
                if (ok) C[(long)r * N + n * 16 + lr] = bf16rne(acc[g][n][j]);
            #pragma unroll
            for (int h = 0; h < H; ++h) {
                float ss = 0.f, sd = 0.f;
                #pragma unroll
                for (int f = 0; f < FPH; ++f) {
                    int n = h * FPH + f;
                    ss += acc[g][n][j] * asv[n];
                    sd += acc[g][n][j] * adv[n];
                }
                #pragma unroll
                for (int o = 8; o > 0; o >>= 1) {
                    ss += __shfl_xor(ss, o);
                    sd += __shfl_xor(sd, o);
                }
                if (ok && lr == 0) {
                    al_s[(long)r * H + h] = ss;
                    al_d[(long)r * H + h] = sd;
                }
            }
        }
    }
}

// --------------- CSR build ---------------------------------------------------
__global__ __launch_bounds__(256) void csr_hist(const int* __restrict__ dst,
                                                int* __restrict__ deg) {
    int i = blockIdx.x * 256 + threadIdx.x;
    if (i >= ETOT) return;
    int d = (i < NE) ? dst[i] : (i - NE);
    atomicAdd(&deg[d], 1);
}

// two-level scan: block-local exclusive prefix + block sums
__global__ __launch_bounds__(1024) void scan1(const int* __restrict__ deg,
                                              int* __restrict__ offp,
                                              int* __restrict__ bsum) {
    __shared__ int wsum[16];
    const int tid = threadIdx.x, lane = tid & 63, w = tid >> 6;
    const int i = blockIdx.x * 1024 + tid;
    int v = (i < NN) ? deg[i] : 0;
    int s = v;
    #pragma unroll
    for (int o = 1; o < 64; o <<= 1) {
        int t = __shfl_up(s, o);
        if (lane >= o) s += t;
    }
    if (lane == 63) wsum[w] = s;
    __syncthreads();
    if (w == 0 && lane < 16) {
        int t = wsum[lane];
        #pragma unroll
        for (int o = 1; o < 16; o <<= 1) {
            int u = __shfl_up(t, o, 16);
            if ((lane & 15) >= o) t += u;
        }
        wsum[lane] = t;
    }
    __syncthreads();
    int woff = (w > 0) ? wsum[w - 1] : 0;
    if (i < NN) offp[i] = woff + s - v;
    if (tid == 0) bsum[blockIdx.x] = wsum[15];
}

// wave0: graph bounds (batch sorted); wave1: scan of block sums
__global__ __launch_bounds__(128) void scan2g(const int* __restrict__ bsum,
                                              int* __restrict__ bpre,
                                              int* __restrict__ offp,
                                              const int* __restrict__ batch,
                                              int* __restrict__ gstart) {
    const int tid = threadIdx.x;
    if (tid < 64) {
        int g = tid;
        int lo = 0, hi = NN;
        while (lo < hi) {
            int mid = (lo + hi) >> 1;
            if (batch[mid] < g) lo = mid + 1; else hi = mid;
        }
        gstart[g] = lo;
        if (tid == 0) gstart[NG] = NN;
    } else {
        int lane = tid - 64;
        int v = (lane < NB_SCAN) ? bsum[lane] : 0;
        int s = v;
        #pragma unroll
        for (int o = 1; o < 64; o <<= 1) {
            int t = __shfl_up(s, o);
            if (lane >= o) s += t;
        }
        if (lane < NB_SCAN) bpre[lane] = s - v;
        if (lane == 63) offp[NN] = s;
    }
}

// add block prefixes + zero the fill cursor (deg buffer, already consumed)
__global__ __launch_bounds__(256) void scan3z(int* __restrict__ offp,
                                              const int* __restrict__ bpre,
                                              int* __restrict__ cur) {
    int i = blockIdx.x * 256 + threadIdx.x;
    if (i < NN) {
        offp[i] += bpre[i >> 10];
        cur[i] = 0;
    }
}

__global__ __launch_bounds__(256) void csr_fill(const int* __restrict__ src,
                                                const int* __restrict__ dst,
                                                const int* __restrict__ offp,
                                                int* __restrict__ cur,
                                                int* __restrict__ csr) {
    int i = blockIdx.x * 256 + threadIdx.x;
    if (i >= ETOT) return;
    int s = (i < NE) ? src[i] : (i - NE);
    int d = (i < NE) ? dst[i] : (i - NE);
    int slot = atomicAdd(&cur[d], 1);
    csr[offp[d] + slot] = s;
}

// --------------- fused softmax + aggregate gather (max-free, 8-deep ILP) -----
template<int H, int C, int RELU, int OUTBF>
__global__ __launch_bounds__(256) void gat_gather(const int* __restrict__ offp,
                                                  const int* __restrict__ csr,
                                                  const float* __restrict__ als,
                                                  const float* __restrict__ ald,
                                                  const unsigned short* __restrict__ Hb,
                                                  const float* __restrict__ bias,
                                                  void* __restrict__ outp_) {
    constexpr int D = H * C;
    constexpr int VPL = D / 64;
    constexpr int HP = (H == 4) ? 5 : 1;   // pad: stride 5 floats, gcd(5,32)=1
    __shared__ float sW[4][64][HP];
    __shared__ int   sS[4][64];
    const int lane = threadIdx.x & 63;
    const int w = threadIdx.x >> 6;
    const int n = blockIdx.x * 4 + w;
    if (n >= NN) return;
    const int h = (lane * VPL) / C;

    float aldv[H];
    #pragma unroll
    for (int hh = 0; hh < H; ++hh) aldv[hh] = ald[(long)n * H + hh];

    float acc[VPL] = {};
    float den = 0.f;

    const int e0 = offp[n], e1 = offp[n + 1];
    for (int base = e0; base < e1; base += 64) {
        const int cntc = min(64, e1 - base);
        const bool valid = lane < cntc;
        const int s_l = valid ? csr[base + lane] : 0;
        if constexpr (H == 4) {
            float4 a4 = *reinterpret_cast<const float4*>(als + (long)s_l * 4);
            float xs[4] = {a4.x, a4.y, a4.z, a4.w};
            #pragma unroll
            for (int hh = 0; hh < 4; ++hh) {
                float x = xs[hh] + aldv[hh];
                x = (x >= 0.f) ? x : NEG * x;
                sW[w][lane][hh] = valid ? expf(x) : 0.f;
            }
        } else {
            float x = als[s_l] + aldv[0];
            x = (x >= 0.f) ? x : NEG * x;
            sW[w][lane][0] = valid ? expf(x) : 0.f;
        }
        sS[w][lane] = s_l;

        int j0 = 0;
        for (; j0 + 8 <= cntc; j0 += 8) {
            int se[8]; float we[8];
            #pragma unroll
            for (int t = 0; t < 8; ++t) {
                se[t] = sS[w][j0 + t];
                we[t] = sW[w][j0 + t][h];
            }
            #pragma unroll
            for (int t = 0; t < 8; ++t) den += we[t];
            if constexpr (VPL == 4) {
                ushort4 aa[8];
                #pragma unroll
                for (int t = 0; t < 8; ++t)
                    aa[t] = *reinterpret_cast<const ushort4*>(Hb + (long)se[t] * D + lane * 4);
                #pragma unroll
                for (int t = 0; t < 8; ++t) {
                    acc[0] += we[t] * bf2f(aa[t].x); acc[1] += we[t] * bf2f(aa[t].y);
                    acc[2] += we[t] * bf2f(aa[t].z); acc[3] += we[t] * bf2f(aa[t].w);
                }
            } else {
                ushort2 aa[8];
                #pragma unroll
                for (int t = 0; t < 8; ++t)
                    aa[t] = *reinterpret_cast<const ushort2*>(Hb + (long)se[t] * D + lane * 2);
                #pragma unroll
                for (int t = 0; t < 8; ++t) {
                    acc[0] += we[t] * bf2f(aa[t].x); acc[1] += we[t] * bf2f(aa[t].y);
                }
            }
        }
        for (; j0 < cntc; j0 += 4) {
            int se[4]; float we[4];
            #pragma unroll
            for (int t = 0; t < 4; ++t) {
                se[t] = sS[w][j0 + t];
                we[t] = sW[w][j0 + t][h];
            }
            #pragma unroll
            for (int t = 0; t < 4; ++t) den += we[t];
            if constexpr (VPL == 4) {
                ushort4 aa[4];
                #pragma unroll
                for (int t = 0; t < 4; ++t)
                    aa[t] = *reinterpret_cast<const ushort4*>(Hb + (long)se[t] * D + lane * 4);
                #pragma unroll
                for (int t = 0; t < 4; ++t) {
                    acc[0] += we[t] * bf2f(aa[t].x); acc[1] += we[t] * bf2f(aa[t].y);
                    acc[2] += we[t] * bf2f(aa[t].z); acc[3] += we[t] * bf2f(aa[t].w);
                }
            } else {
                ushort2 aa[4];
                #pragma unroll
                for (int t = 0; t < 4; ++t)
                    aa[t] = *reinterpret_cast<const ushort2*>(Hb + (long)se[t] * D + lane * 2);
                #pragma unroll
                for (int t = 0; t < 4; ++t) {
                    acc[0] += we[t] * bf2f(aa[t].x); acc[1] += we[t] * bf2f(aa[t].y);
                }
            }
        }
    }
    float inv = 1.f / den;   // self-loop guarantees den > 0
    float v[VPL];
    #pragma unroll
    for (int k = 0; k < VPL; ++k) {
        v[k] = acc[k] * inv + bias[lane * VPL + k];
        if (RELU) v[k] = fmaxf(v[k], 0.f);
    }
    if constexpr (OUTBF) {
        unsigned short* o = (unsigned short*)outp_;
        if constexpr (VPL == 4) {
            ushort4 p; p.x = bf16rne(v[0]); p.y = bf16rne(v[1]);
            p.z = bf16rne(v[2]); p.w = bf16rne(v[3]);
            *reinterpret_cast<ushort4*>(o + (long)n * D + lane * 4) = p;
        } else {
            ushort2 p; p.x = bf16rne(v[0]); p.y = bf16rne(v[1]);
            *reinterpret_cast<ushort2*>(o + (long)n * D + lane * 2) = p;
        }
    } else {
        float* o = (float*)outp_;
        if constexpr (VPL == 4) {
            float4 p = {v[0], v[1], v[2], v[3]};
            *reinterpret_cast<float4*>(o + (long)n * D + lane * 4) = p;
        } else {
            float2 p = {v[0], v[1]};
            *reinterpret_cast<float2*>(o + (long)n * D + lane * 2) = p;
        }
    }
}

// --------------- pooling (bf16 input; batch sorted) --------------------------
__global__ __launch_bounds__(256) void pool_graph(const unsigned short* __restrict__ out2b,
                                                  const int* __restrict__ gstart,
                                                  float* __restrict__ out) {
    __shared__ float2 part[4][64];
    const int g = blockIdx.x;
    const int ch2 = threadIdx.x & 63;     // channel pair
    const int q = threadIdx.x >> 6;       // row group 0..3
    const int s = gstart[g], e = gstart[g + 1];
    float2 acc = {0.f, 0.f};
    for (int r = s + q; r < e; r += 4) {
        ushort2 v = *reinterpret_cast<const ushort2*>(out2b + (long)r * D2 + ch2 * 2);
        acc.x += bf2f(v.x);
        acc.y += bf2f(v.y);
    }
    part[q][ch2] = acc;
    __syncthreads();
    if (q == 0) {
        float inv = 1.f / fmaxf((float)(e - s), 1.f);
        float2 v;
        v.x = (part[0][ch2].x + part[1][ch2].x + part[2][ch2].x + part[3][ch2].x) * inv;
        v.y = (part[0][ch2].y + part[1][ch2].y + part[2][ch2].y + part[3][ch2].y) * inv;
        *reinterpret_cast<float2*>(out + g * D2 + ch2 * 2) = v;
    }
}

extern "C" void kernel_launch(void* const* d_in, const int* in_sizes, int n_in,
                              void* d_out, int out_size, void* d_ws, size_t ws_size,
                              hipStream_t stream) {
    const float* x      = (const float*)d_in[0];
    const int*   src    = (const int*)d_in[1];
    const int*   dst    = (const int*)d_in[2];
    const int*   batch  = (const int*)d_in[3];
    const float* W1     = (const float*)d_in[4];
    const float* a_src1 = (const float*)d_in[5];
    const float* a_dst1 = (const float*)d_in[6];
    const float* b1     = (const float*)d_in[7];
    const float* W2     = (const float*)d_in[8];
    const float* a_src2 = (const float*)d_in[9];
    const float* a_dst2 = (const float*)d_in[10];
    const float* b2     = (const float*)d_in[11];
    float* out = (float*)d_out;

    // workspace layout (~96 MB), all bf16 arrays 16B-aligned
    float* ws   = (float*)d_ws;
    float* als1 = ws;                              // [NN*4]
    float* ald1 = als1 + (long)NN * H1HEADS;       // [NN*4]
    float* als2 = als1;                            // [NN] alias (layer1 dead then)
    float* ald2 = als1 + NN;                       // [NN]
    unsigned short* xb    = (unsigned short*)(ald1 + (long)NN * H1HEADS); // [NN*128]
    unsigned short* Hb1   = xb + (long)NN * IND;    // [NN*256]
    unsigned short* out1b = Hb1 + (long)NN * D1;    // [NN*256]
    unsigned short* Hb2   = out1b + (long)NN * D1;  // [NN*128]
    unsigned short* out2b = Hb2 + (long)NN * D2;    // [NN*128]
    unsigned short* W1t   = out2b + (long)NN * D2;  // [256*128]
    unsigned short* W2t   = W1t + D1 * IND;         // [128*256]
    int* deg    = (int*)(W2t + D2 * D1);            // [NN] (also fill cursor)
    int* offp   = deg + NN;                         // [NN+1]
    int* csr    = offp + NN + 1;                    // [ETOT]
    int* gstart = csr + ETOT;                       // [NG+1]
    int* bsum   = gstart + NG + 1;                  // [NB_SCAN]
    int* bpre   = bsum + NB_SCAN;                   // [NB_SCAN]

    // ---- prep (fused) + CSR build + graph bounds ----
    {
        long total = (long)NN * IND / 4 + IND * D1 + D1 * D2 + NN;
        prep_all<<<(int)((total + 255) / 256), 256, 0, stream>>>(x, xb, W1, W1t, W2, W2t, deg);
    }
    csr_hist<<<(ETOT + 255) / 256, 256, 0, stream>>>(dst, deg);
    scan1<<<NB_SCAN, 1024, 0, stream>>>(deg, offp, bsum);
    scan2g<<<1, 128, 0, stream>>>(bsum, bpre, offp, batch, gstart);
    scan3z<<<(NN + 255) / 256, 256, 0, stream>>>(offp, bpre, deg);
    csr_fill<<<(ETOT + 255) / 256, 256, 0, stream>>>(src, dst, offp, deg, csr);

    // ---- layer 1 ----
    mfma_gemm_sc<IND, D1, H1HEADS><<<(NN + 127) / 128, 256, 0, stream>>>(
        NN, xb, W1t, a_src1, a_dst1, Hb1, als1, ald1);
    gat_gather<H1HEADS, HID1, 1, 1><<<(NN + 3) / 4, 256, 0, stream>>>(
        offp, csr, als1, ald1, Hb1, b1, out1b);

    // ---- layer 2 ----
    mfma_gemm_sc<D1, D2, 1><<<(NN + 127) / 128, 256, 0, stream>>>(
        NN, out1b, W2t, a_src2, a_dst2, Hb2, als2, ald2);
    gat_gather<1, D2, 0, 1><<<(NN + 3) / 4, 256, 0, stream>>>(
        offp, csr, als2, ald2, Hb2, b2, out2b);

    // ---- pool ----
    pool_graph<<<NG, 256, 0, stream>>>(out2b, gstart, out);
}